// Round 5
// baseline (426.337 us; speedup 1.0000x reference)
//
#include <hip/hip_runtime.h>

// NodeEncoder: RoIAlign -> FC1(12544->512)+BN+ReLU -> FC2(512->512)+BN+ReLU -> max over K=8
// F=64 C=256 H=W=40, N=512 K=8 (R=4096), ROI=7, HID=D=512
// NOTE: harness re-poisons 400MiB d_ws (~61us fill) + restores inputs (~45us) inside the
// timed region -> ~106us fixed overhead. Kernel budget is what we optimize.
//
// R14: transpose+gather pinned at ~1.9TB/s invariant to occupancy (R10), order (R12),
// run-length (R13) -> stop tuning, DELETE the imgTb intermediate (52MB write + 52MB read).
// Fused roi: block=(frame, 32ch-group) loads [32][1600] f32 slice -> LDS bf16 (102.7KB),
// interpolates all RoIs of the frame (perm+fstart), writes A directly in 64-B sectors.
// prep shrinks to w1/w2/sort. Predicted: prep 70->~10us, roi_fused ~35-55us.

typedef __bf16 bf16x8 __attribute__((ext_vector_type(8)));
typedef float f32x4 __attribute__((ext_vector_type(4)));
typedef ushort us8v __attribute__((ext_vector_type(8)));

#define BN_EPS 1e-3f

__device__ __forceinline__ ushort f2bf(float f) {
  union { float f; unsigned u; } v; v.f = f;
  unsigned r = (v.u + 0x7FFFu + ((v.u >> 16) & 1u)) >> 16;
  return (ushort)r;
}
__device__ __forceinline__ float bf2f(ushort b) {
  union { unsigned u; float f; } v; v.u = ((unsigned)b) << 16;
  return v.f;
}
__device__ __forceinline__ void async16(const void* g, void* l) {
  __builtin_amdgcn_global_load_lds((const __attribute__((address_space(1))) void*)g,
                                   (__attribute__((address_space(3))) void*)l, 16, 0, 0);
}

// ------- 1. prep: w1 conv (blocks 0..511) | w2 conv (512..767) | RoI sort+fstart (768) --
__global__ __launch_bounds__(256) void prep_kernel(const float* __restrict__ w1,
                                                   ushort* __restrict__ w1b,
                                                   const float* __restrict__ w2,
                                                   ushort* __restrict__ w2b,
                                                   const int* __restrict__ kf,
                                                   int* __restrict__ perm,
                                                   int* __restrict__ fstart) {
  __shared__ __align__(16) char smem[25480];
  const int b = blockIdx.x;
  const int tid = threadIdx.x;
  if (b < 512) {
    // w1 [512][256][49] f32 -> w1b [512][49*256] bf16 (k = p*256+c); bf16 staging
    ushort* t = (ushort*)smem;  // [p][c], pitch 260, 49 rows = 25,480B
    const float* src = w1 + (size_t)b * 12544;
    for (int j = tid; j < 12544; j += 256) {
      int c = j / 49, p = j - c * 49;
      t[p * 260 + c] = f2bf(src[j]);
    }
    __syncthreads();
    ushort* dst = w1b + (size_t)b * 12544;
    for (int k0 = tid * 8; k0 < 12544; k0 += 2048) {
      int p = k0 >> 8, c = k0 & 255;
      ushort4 a = *(const ushort4*)(&t[p * 260 + c]);
      ushort4 d = *(const ushort4*)(&t[p * 260 + c + 4]);
      us8v o8;
      o8[0] = a.x; o8[1] = a.y; o8[2] = a.z; o8[3] = a.w;
      o8[4] = d.x; o8[5] = d.y; o8[6] = d.z; o8[7] = d.w;
      *(us8v*)(dst + k0) = o8;
    }
  } else if (b < 768) {
    // w2 [512][512] f32 -> bf16, float4 per thread
    const int o2 = b - 512;
    const size_t base = (size_t)o2 * 1024 + tid * 4;
    float4 vv = *(const float4*)(w2 + base);
    ushort4 o4;
    o4.x = f2bf(vv.x); o4.y = f2bf(vv.y); o4.z = f2bf(vv.z); o4.w = f2bf(vv.w);
    *(ushort4*)(w2b + base) = o4;
  } else {
    // counting sort of RoIs by frame -> perm[4096], frame boundaries -> fstart[65]
    int* cnt = (int*)smem;
    int* base = cnt + 64;
    if (tid < 64) cnt[tid] = 0;
    __syncthreads();
    for (int r = tid; r < 4096; r += 256) atomicAdd(&cnt[kf[r]], 1);
    __syncthreads();
    if (tid == 0) {
      int acc = 0;
      for (int f = 0; f < 64; ++f) { base[f] = acc; fstart[f] = acc; acc += cnt[f]; }
      fstart[64] = acc;  // = 4096
    }
    __syncthreads();
    for (int r = tid; r < 4096; r += 256) {
      int p = atomicAdd(&base[kf[r]], 1);
      perm[p] = r;
    }
  }
}

// ------- 2. fused transpose+RoIAlign -> A [4096][12544] bf16, k = (py*7+px)*256 + c -----
// block = (frame f, channel-group cg of 32): load images[f, cg*32..cg*32+31, :, :] f32
// (coalesced 6.4KB runs) -> LDS bf16 [32][1604] (pitch 1604: 8B-aligned rows, dword
// stride 802 -> ch-major reads hit 16 banks = 2-way, free). Then every RoI of frame f:
// 1568 items (49 pos x 32 ch), full per-item setup (no syncs), write bf16 to A.
// Per (roi,pos): 32ch x 2B = one aligned 64-B sector -> no write amplification.
__global__ __launch_bounds__(512) void roi_fused_kernel(const float* __restrict__ img,
                                                        const float* __restrict__ boxes,
                                                        const int* __restrict__ perm,
                                                        const int* __restrict__ fstart,
                                                        ushort* __restrict__ A) {
  __shared__ ushort lds[32 * 1604];  // 102,656 B
  const int tid = threadIdx.x;
  const int f = blockIdx.x >> 3, cg = blockIdx.x & 7;
  const float* src = img + (size_t)f * 409600 + (size_t)(cg * 32) * 1600;
  // load: 12800 float4 (=32ch x 400), each -> ushort4 store (8B-aligned, conflict-free)
  for (int i = tid; i < 12800; i += 512) {
    int ch = i / 400, pos = i - ch * 400;
    float4 v = *(const float4*)(src + (size_t)ch * 1600 + pos * 4);
    ushort4 o;
    o.x = f2bf(v.x); o.y = f2bf(v.y); o.z = f2bf(v.z); o.w = f2bf(v.w);
    *(ushort4*)(&lds[ch * 1604 + pos * 4]) = o;
  }
  __syncthreads();
  const int s0 = fstart[f], s1 = fstart[f + 1];
  ushort* Abase = A + cg * 32;
  for (int idx = s0; idx < s1; ++idx) {
    const int r = perm[idx];
    const float bx1 = boxes[r * 4 + 0] * 40.f, by1 = boxes[r * 4 + 1] * 40.f;
    const float bx2 = boxes[r * 4 + 2] * 40.f, by2 = boxes[r * 4 + 3] * 40.f;
    const float bw = (bx2 - bx1) * (1.f / 7.f), bh = (by2 - by1) * (1.f / 7.f);
    ushort* outp = Abase + (size_t)r * 12544;
    for (int it = tid; it < 1568; it += 512) {
      const int p = it >> 5, ch = it & 31;
      const int py = p / 7, px = p - py * 7;
      const float X = bx1 + (px + 0.5f) * bw, Y = by1 + (py + 0.5f) * bh;
      const bool valid = (X > -1.f) && (X < 40.f) && (Y > -1.f) && (Y < 40.f);
      const float x = fminf(fmaxf(X, 0.f), 39.f), y = fminf(fmaxf(Y, 0.f), 39.f);
      const float x0f = floorf(x), y0f = floorf(y);
      const int x0 = (int)x0f, y0 = (int)y0f;
      const int x1i = min(x0 + 1, 39), y1i = min(y0 + 1, 39);
      const float lx = x - x0f, ly = y - y0f;
      const float vm = valid ? 1.f : 0.f;
      const float w00 = (1.f - ly) * (1.f - lx) * vm;
      const float w01 = (1.f - ly) * lx * vm;
      const float w10 = ly * (1.f - lx) * vm;
      const float w11 = ly * lx * vm;
      const ushort* row = &lds[ch * 1604];
      const float a = bf2f(row[y0 * 40 + x0]);
      const float b = bf2f(row[y0 * 40 + x1i]);
      const float c = bf2f(row[y1i * 40 + x0]);
      const float d = bf2f(row[y1i * 40 + x1i]);
      outp[p * 256 + ch] = f2bf(a * w00 + b * w01 + c * w10 + d * w11);
    }
  }
}

// ------- 3. GEMM1: [4096,12544]x[512,12544]^T bf16, BK=64, split-K=7, bf16 partials ------
// __launch_bounds__(256,4): force <=128 unified regs/wave (64 acc AGPR + <=64 VGPR) so
// 4 blocks/CU fit (was 3 at 140 regs) -> more cross-block overlap of the barrier drain.
// LDS swizzle (BK=64, 8 chunks/row): slot s of row R holds global chunk s ^ (R&7).
__global__ __launch_bounds__(256, 4) void gemm1_kernel(const ushort* __restrict__ A,
                                                       const ushort* __restrict__ B,
                                                       ushort* __restrict__ P) {
  constexpr int K = 12544;
  constexpr int KS = 1792;  // = K/7, 28 iters of 64
  __shared__ __align__(16) ushort sA[128 * 64];  // 16 KB
  __shared__ __align__(16) ushort sB[128 * 64];  // 16 KB
  const int tid = threadIdx.x;
  const int lane = tid & 63, wave = tid >> 6;
  const int wm = wave >> 1, wn = wave & 1;
  const int r16 = lane & 15, quad = lane >> 4;
  const int r0 = blockIdx.x * 128, c0 = blockIdx.y * 128;
  const int kStart = blockIdx.z * KS, kEnd = kStart + KS;
  const ushort* Ab = A + (size_t)r0 * K;
  const ushort* Bb = B + (size_t)c0 * K;
  const int row8 = tid >> 3;                        // 0..31
  const int koff = (((tid & 7) ^ (row8 & 7))) * 8;  // swizzled source chunk offset
  const int sw = r16 & 7;
  f32x4 acc[4][4] = {};
  for (int kk = kStart; kk < kEnd; kk += 64) {
    __syncthreads();
#pragma unroll
    for (int s = 0; s < 4; ++s)
      async16(Ab + (size_t)(s * 32 + row8) * K + kk + koff, (char*)sA + s * 4096 + tid * 16);
#pragma unroll
    for (int s = 0; s < 4; ++s)
      async16(Bb + (size_t)(s * 32 + row8) * K + kk + koff, (char*)sB + s * 4096 + tid * 16);
    __syncthreads();
#pragma unroll
    for (int h = 0; h < 2; ++h) {
      const int slot = ((h * 4 + quad) ^ sw) * 8;
      bf16x8 af[4], bfr[4];
#pragma unroll
      for (int i = 0; i < 4; ++i)
        af[i] = *(const bf16x8*)(sA + (wm * 64 + i * 16 + r16) * 64 + slot);
#pragma unroll
      for (int j = 0; j < 4; ++j)
        bfr[j] = *(const bf16x8*)(sB + (wn * 64 + j * 16 + r16) * 64 + slot);
#pragma unroll
      for (int i = 0; i < 4; ++i)
#pragma unroll
        for (int j = 0; j < 4; ++j)
          acc[i][j] = __builtin_amdgcn_mfma_f32_16x16x32_bf16(af[i], bfr[j], acc[i][j], 0, 0, 0);
    }
  }
  ushort* Pz = P + ((size_t)blockIdx.z * 4096 + r0) * 512 + c0;
#pragma unroll
  for (int i = 0; i < 4; ++i)
#pragma unroll
    for (int j = 0; j < 4; ++j)
#pragma unroll
      for (int g = 0; g < 4; ++g)
        Pz[(size_t)(wm * 64 + i * 16 + quad * 4 + g) * 512 + (wn * 64 + j * 16 + r16)] =
            f2bf(acc[i][j][g]);
}

// ------- 4. combine 7 split-K bf16 partials + b1 + BN1 + ReLU -> h1 bf16 -----------------
__global__ __launch_bounds__(256) void combine_kernel(const ushort* __restrict__ P,
                                                      const float* __restrict__ b1,
                                                      const float* __restrict__ g1,
                                                      const float* __restrict__ bt1,
                                                      const float* __restrict__ m1,
                                                      const float* __restrict__ v1,
                                                      ushort* __restrict__ h1) {
  size_t i = (size_t)blockIdx.x * 256 + threadIdx.x;  // exactly 4096*512
  int col = (int)(i & 511);
  float x = 0.f;
#pragma unroll
  for (int z = 0; z < 7; ++z) x += bf2f(P[i + (size_t)z * 2097152]);
  float s = g1[col] * rsqrtf(v1[col] + BN_EPS);
  float val = fmaxf((x + b1[col] - m1[col]) * s + bt1[col], 0.f);
  h1[i] = f2bf(val);
}

// ------- 5. GEMM2 (64x128 tile, BK=64) + b2 + BN2 + ReLU + group-of-8 max -> out ---------
__global__ __launch_bounds__(256) void gemm2_kernel(const ushort* __restrict__ A,
                                                    const ushort* __restrict__ B,
                                                    const float* __restrict__ b2,
                                                    const float* __restrict__ g2,
                                                    const float* __restrict__ bt2,
                                                    const float* __restrict__ m2,
                                                    const float* __restrict__ v2,
                                                    float* __restrict__ out) {
  constexpr int K = 512;
  __shared__ __align__(16) ushort sA[64 * 64];   // 8 KB
  __shared__ __align__(16) ushort sB[128 * 64];  // 16 KB
  __shared__ ushort st[64 * 128];                // post-activation tile for group-max
  const int tid = threadIdx.x;
  const int lane = tid & 63, wave = tid >> 6;
  const int wm = wave >> 1, wn = wave & 1;
  const int r16 = lane & 15, quad = lane >> 4;
  const int r0 = blockIdx.x * 64, c0 = blockIdx.y * 128;
  const ushort* Ab = A + (size_t)r0 * K;
  const ushort* Bb = B + (size_t)c0 * K;
  const int row8 = tid >> 3;
  const int koff = (((tid & 7) ^ (row8 & 7))) * 8;
  const int sw = r16 & 7;
  f32x4 acc[2][4] = {};
  for (int kk = 0; kk < K; kk += 64) {
    __syncthreads();
#pragma unroll
    for (int s = 0; s < 2; ++s)
      async16(Ab + (size_t)(s * 32 + row8) * K + kk + koff, (char*)sA + s * 4096 + tid * 16);
#pragma unroll
    for (int s = 0; s < 4; ++s)
      async16(Bb + (size_t)(s * 32 + row8) * K + kk + koff, (char*)sB + s * 4096 + tid * 16);
    __syncthreads();
#pragma unroll
    for (int h = 0; h < 2; ++h) {
      const int slot = ((h * 4 + quad) ^ sw) * 8;
      bf16x8 af[2], bfr[4];
#pragma unroll
      for (int i = 0; i < 2; ++i)
        af[i] = *(const bf16x8*)(sA + (wm * 32 + i * 16 + r16) * 64 + slot);
#pragma unroll
      for (int j = 0; j < 4; ++j)
        bfr[j] = *(const bf16x8*)(sB + (wn * 64 + j * 16 + r16) * 64 + slot);
#pragma unroll
      for (int i = 0; i < 2; ++i)
#pragma unroll
        for (int j = 0; j < 4; ++j)
          acc[i][j] = __builtin_amdgcn_mfma_f32_16x16x32_bf16(af[i], bfr[j], acc[i][j], 0, 0, 0);
    }
  }
  float ss[4], tt[4], bbv[4];
#pragma unroll
  for (int j = 0; j < 4; ++j) {
    int c = c0 + wn * 64 + j * 16 + r16;
    float s = g2[c] * rsqrtf(v2[c] + BN_EPS);
    ss[j] = s; tt[j] = bt2[c] - m2[c] * s; bbv[j] = b2[c];
  }
#pragma unroll
  for (int i = 0; i < 2; ++i)
#pragma unroll
    for (int j = 0; j < 4; ++j)
#pragma unroll
      for (int g = 0; g < 4; ++g) {
        int rr = wm * 32 + i * 16 + quad * 4 + g;
        int cc = wn * 64 + j * 16 + r16;
        float x = (acc[i][j][g] + bbv[j]) * ss[j] + tt[j];
        st[rr * 128 + cc] = f2bf(fmaxf(x, 0.f));
      }
  __syncthreads();
  for (int e = tid; e < 1024; e += 256) {
    int gg = e >> 7, cc = e & 127;
    float m = 0.f;  // relu output >= 0
#pragma unroll
    for (int k = 0; k < 8; ++k) m = fmaxf(m, bf2f(st[(gg * 8 + k) * 128 + cc]));
    out[(size_t)(r0 / 8 + gg) * 512 + c0 + cc] = m;
  }
}

extern "C" void kernel_launch(void* const* d_in, const int* in_sizes, int n_in,
                              void* d_out, int out_size, void* d_ws, size_t ws_size,
                              hipStream_t stream) {
  (void)in_sizes; (void)n_in; (void)out_size; (void)ws_size;
  const float* images = (const float*)d_in[0];
  const int* kf      = (const int*)d_in[1];
  const float* boxes = (const float*)d_in[2];
  const float* w1    = (const float*)d_in[3];
  const float* b1    = (const float*)d_in[4];
  const float* g1    = (const float*)d_in[5];
  const float* bt1   = (const float*)d_in[6];
  const float* m1    = (const float*)d_in[7];
  const float* v1    = (const float*)d_in[8];
  const float* w2    = (const float*)d_in[9];
  const float* b2    = (const float*)d_in[10];
  const float* g2    = (const float*)d_in[11];
  const float* bt2   = (const float*)d_in[12];
  const float* m2    = (const float*)d_in[13];
  const float* v2    = (const float*)d_in[14];
  float* out = (float*)d_out;

  char* ws = (char*)d_ws;
  // layout (bytes):  [ws_size >= 221 MB proven earlier; imgTb eliminated in R14]
  //   A      @ 0          : 4096*12544*2 = 102,760,448
  //   w1b    @ 102,760,448: 512*12544*2  =  12,845,056
  //   w2b    @ 115,605,504: 512*512*2    =     524,288
  //   P      @ 116,129,792: 7*4096*512*2 = 29,360,128
  //   h1     @ 149,684,224: 4096*512*2   =   4,194,304
  //   perm   @ 168,558,592: 4096*4       =      16,384
  //   fstart @ 168,574,976: 65*4         =         260
  ushort* Abuf  = (ushort*)(ws + 0);
  ushort* w1b   = (ushort*)(ws + 102760448);
  ushort* w2b   = (ushort*)(ws + 115605504);
  ushort* P     = (ushort*)(ws + 116129792);
  ushort* h1    = (ushort*)(ws + 149684224);
  int*    perm  = (int*)(ws + 168558592);
  int*    fstart= (int*)(ws + 168574976);

  hipLaunchKernelGGL(prep_kernel, dim3(769), dim3(256), 0, stream,
                     w1, w1b, w2, w2b, kf, perm, fstart);
  hipLaunchKernelGGL(roi_fused_kernel, dim3(512), dim3(512), 0, stream,
                     images, boxes, perm, fstart, Abuf);
  hipLaunchKernelGGL(gemm1_kernel, dim3(32, 4, 7), dim3(256), 0, stream, Abuf, w1b, P);
  hipLaunchKernelGGL(combine_kernel, dim3(8192), dim3(256), 0, stream, P, b1, g1, bt1, m1, v1, h1);
  hipLaunchKernelGGL(gemm2_kernel, dim3(64, 4), dim3(256), 0, stream, h1, w2b, b2, g2, bt2, m2, v2, out);
}

// Round 6
// 388.422 us; speedup vs baseline: 1.0976x; 1.0976x over previous
//
#include <hip/hip_runtime.h>

// NodeEncoder: RoIAlign -> FC1(12544->512)+BN+ReLU -> FC2(512->512)+BN+ReLU -> max over K=8
// F=64 C=256 H=W=40, N=512 K=8 (R=4096), ROI=7, HID=D=512
// NOTE: harness re-poisons 400MiB d_ws (~61us fill) + restores inputs (~45us) inside the
// timed region -> ~106us fixed overhead. Kernel budget is what we optimize.
//
// R15: R14's fused roi was VALU/latency-bound (setup recomputed per-channel = 32x
// redundant; 1 blk/CU @ 512thr = 2 waves/SIMD). Fix: precompute per-(roi,pos) packed
// corner idx + float4 weights in prep (200,704 items, 4MB ws); roi inner loop = 2
// broadcast loads + 4 LDS u16 + 4 FMA. 1024-thread blocks (16 waves/CU at same 102.6KB
// LDS). Writes stay full 64-B sectors. Predicted roi_fused 201 -> 40-55us.

typedef __bf16 bf16x8 __attribute__((ext_vector_type(8)));
typedef float f32x4 __attribute__((ext_vector_type(4)));
typedef ushort us8v __attribute__((ext_vector_type(8)));

#define BN_EPS 1e-3f

__device__ __forceinline__ ushort f2bf(float f) {
  union { float f; unsigned u; } v; v.f = f;
  unsigned r = (v.u + 0x7FFFu + ((v.u >> 16) & 1u)) >> 16;
  return (ushort)r;
}
__device__ __forceinline__ float bf2f(ushort b) {
  union { unsigned u; float f; } v; v.u = ((unsigned)b) << 16;
  return v.f;
}
__device__ __forceinline__ void async16(const void* g, void* l) {
  __builtin_amdgcn_global_load_lds((const __attribute__((address_space(1))) void*)g,
                                   (__attribute__((address_space(3))) void*)l, 16, 0, 0);
}

// ------- 1. prep: w1 conv (0..511) | w2 conv (512..767) | sort+fstart (768)
//            | RoI setup precompute (769..866: 98 blocks x 2048 items = 200,704 exactly)
__global__ __launch_bounds__(256) void prep_kernel(const float* __restrict__ w1,
                                                   ushort* __restrict__ w1b,
                                                   const float* __restrict__ w2,
                                                   ushort* __restrict__ w2b,
                                                   const int* __restrict__ kf,
                                                   const float* __restrict__ boxes,
                                                   int* __restrict__ perm,
                                                   int* __restrict__ fstart,
                                                   uint* __restrict__ widx,
                                                   float4* __restrict__ wts) {
  __shared__ __align__(16) char smem[25480];
  const int b = blockIdx.x;
  const int tid = threadIdx.x;
  if (b < 512) {
    // w1 [512][256][49] f32 -> w1b [512][49*256] bf16 (k = p*256+c); bf16 staging
    ushort* t = (ushort*)smem;  // [p][c], pitch 260, 49 rows = 25,480B
    const float* src = w1 + (size_t)b * 12544;
    for (int j = tid; j < 12544; j += 256) {
      int c = j / 49, p = j - c * 49;
      t[p * 260 + c] = f2bf(src[j]);
    }
    __syncthreads();
    ushort* dst = w1b + (size_t)b * 12544;
    for (int k0 = tid * 8; k0 < 12544; k0 += 2048) {
      int p = k0 >> 8, c = k0 & 255;
      ushort4 a = *(const ushort4*)(&t[p * 260 + c]);
      ushort4 d = *(const ushort4*)(&t[p * 260 + c + 4]);
      us8v o8;
      o8[0] = a.x; o8[1] = a.y; o8[2] = a.z; o8[3] = a.w;
      o8[4] = d.x; o8[5] = d.y; o8[6] = d.z; o8[7] = d.w;
      *(us8v*)(dst + k0) = o8;
    }
  } else if (b < 768) {
    // w2 [512][512] f32 -> bf16, float4 per thread
    const int o2 = b - 512;
    const size_t base = (size_t)o2 * 1024 + tid * 4;
    float4 vv = *(const float4*)(w2 + base);
    ushort4 o4;
    o4.x = f2bf(vv.x); o4.y = f2bf(vv.y); o4.z = f2bf(vv.z); o4.w = f2bf(vv.w);
    *(ushort4*)(w2b + base) = o4;
  } else if (b == 768) {
    // counting sort of RoIs by frame -> perm[4096], frame boundaries -> fstart[65]
    int* cnt = (int*)smem;
    int* base = cnt + 64;
    if (tid < 64) cnt[tid] = 0;
    __syncthreads();
    for (int r = tid; r < 4096; r += 256) atomicAdd(&cnt[kf[r]], 1);
    __syncthreads();
    if (tid == 0) {
      int acc = 0;
      for (int f = 0; f < 64; ++f) { base[f] = acc; fstart[f] = acc; acc += cnt[f]; }
      fstart[64] = acc;  // = 4096
    }
    __syncthreads();
    for (int r = tid; r < 4096; r += 256) {
      int p = atomicAdd(&base[kf[r]], 1);
      perm[p] = r;
    }
  } else {
    // RoI interp setup: for each (r, p) of 4096x49: packed corner idx + float4 weights
    const int i0 = (b - 769) * 2048 + tid * 8;
#pragma unroll
    for (int e = 0; e < 8; ++e) {
      const int idx = i0 + e;  // < 200,704 guaranteed (98*2048 exact)
      const int r = idx / 49, p = idx - r * 49;
      const int py = p / 7, px = p - py * 7;
      const float x1 = boxes[r * 4 + 0] * 40.f, y1 = boxes[r * 4 + 1] * 40.f;
      const float x2 = boxes[r * 4 + 2] * 40.f, y2 = boxes[r * 4 + 3] * 40.f;
      const float bw = (x2 - x1) * (1.f / 7.f), bh = (y2 - y1) * (1.f / 7.f);
      const float X = x1 + (px + 0.5f) * bw, Y = y1 + (py + 0.5f) * bh;
      const bool valid = (X > -1.f) && (X < 40.f) && (Y > -1.f) && (Y < 40.f);
      const float x = fminf(fmaxf(X, 0.f), 39.f), y = fminf(fmaxf(Y, 0.f), 39.f);
      const float x0f = floorf(x), y0f = floorf(y);
      const int x0 = (int)x0f, y0 = (int)y0f;
      const int x1i = min(x0 + 1, 39), y1i = min(y0 + 1, 39);
      const float lx = x - x0f, ly = y - y0f;
      const float vm = valid ? 1.f : 0.f;
      const uint o00 = (uint)(y0 * 40 + x0);
      const uint dx = (uint)(x1i - x0);        // 0 or 1
      const uint dyf = (uint)(y1i - y0);       // 0 or 1 (means +40)
      widx[idx] = o00 | (dx << 11) | (dyf << 12);
      wts[idx] = make_float4((1.f - ly) * (1.f - lx) * vm, (1.f - ly) * lx * vm,
                             ly * (1.f - lx) * vm, ly * lx * vm);
    }
  }
}

// ------- 2. fused transpose+RoIAlign -> A [4096][12544] bf16, k = (py*7+px)*256 + c -----
// block = (frame f, channel-group cg of 32): load images[f, cg*32.., :, :] f32 coalesced
// -> LDS bf16 [32][1604] (pitch 1604: interp reads by 32 lanes sharing p hit banks
// chl*2 mod 32 = 2-way = free). Then per RoI of frame f: it = p*32+chl, setup loads are
// 32-lane broadcast (widx/wts precomputed), 4 LDS u16 + 4 FMA, write = 64-B sector.
// 1024 threads, 1 block/CU (102.6KB LDS) -> 16 waves/CU.
__global__ __launch_bounds__(1024) void roi_fused_kernel(const float* __restrict__ img,
                                                         const int* __restrict__ perm,
                                                         const int* __restrict__ fstart,
                                                         const uint* __restrict__ widx,
                                                         const float4* __restrict__ wts,
                                                         ushort* __restrict__ A) {
  __shared__ ushort lds[32 * 1604];  // 102,656 B
  const int tid = threadIdx.x;
  const int f = blockIdx.x >> 3, cg = blockIdx.x & 7;
  const float* src = img + (size_t)f * 409600 + (size_t)(cg * 32) * 1600;
  // load: 12800 float4 (=32ch x 400 quads) -> ushort4 stores (8B-aligned)
  for (int i = tid; i < 12800; i += 1024) {
    int ch = i / 400, pos = i - ch * 400;
    float4 v = *(const float4*)(src + (size_t)ch * 1600 + pos * 4);
    ushort4 o;
    o.x = f2bf(v.x); o.y = f2bf(v.y); o.z = f2bf(v.z); o.w = f2bf(v.w);
    *(ushort4*)(&lds[ch * 1604 + pos * 4]) = o;
  }
  __syncthreads();
  const int s0 = fstart[f], s1 = fstart[f + 1];
  const int chl = tid & 31;
  const ushort* lrow = &lds[chl * 1604];
  ushort* Abase = A + cg * 32 + chl;
  for (int idx = s0; idx < s1; ++idx) {
    const int r = perm[idx];
    const uint* wip = widx + r * 49;
    const float4* wwp = wts + r * 49;
    ushort* outp = Abase + (size_t)r * 12544;
    for (int it = tid; it < 1568; it += 1024) {
      const int p = it >> 5;
      const uint pk = wip[p];          // broadcast across 32 lanes sharing p
      const float4 w = wwp[p];         // broadcast
      const int o00 = (int)(pk & 2047u);
      const int dx = (int)((pk >> 11) & 1u);
      const int dy = ((pk >> 12) & 1u) ? 40 : 0;
      const float a = bf2f(lrow[o00]);
      const float b = bf2f(lrow[o00 + dx]);
      const float c = bf2f(lrow[o00 + dy]);
      const float d = bf2f(lrow[o00 + dx + dy]);
      outp[p * 256] = f2bf(a * w.x + b * w.y + c * w.z + d * w.w);
    }
  }
}

// ------- 3. GEMM1: [4096,12544]x[512,12544]^T bf16, BK=64, split-K=7, bf16 partials ------
// __launch_bounds__(256,4): force <=128 unified regs/wave (64 acc AGPR + <=64 VGPR) so
// 4 blocks/CU fit (was 3 at 140 regs) -> more cross-block overlap of the barrier drain.
// LDS swizzle (BK=64, 8 chunks/row): slot s of row R holds global chunk s ^ (R&7).
__global__ __launch_bounds__(256, 4) void gemm1_kernel(const ushort* __restrict__ A,
                                                       const ushort* __restrict__ B,
                                                       ushort* __restrict__ P) {
  constexpr int K = 12544;
  constexpr int KS = 1792;  // = K/7, 28 iters of 64
  __shared__ __align__(16) ushort sA[128 * 64];  // 16 KB
  __shared__ __align__(16) ushort sB[128 * 64];  // 16 KB
  const int tid = threadIdx.x;
  const int lane = tid & 63, wave = tid >> 6;
  const int wm = wave >> 1, wn = wave & 1;
  const int r16 = lane & 15, quad = lane >> 4;
  const int r0 = blockIdx.x * 128, c0 = blockIdx.y * 128;
  const int kStart = blockIdx.z * KS, kEnd = kStart + KS;
  const ushort* Ab = A + (size_t)r0 * K;
  const ushort* Bb = B + (size_t)c0 * K;
  const int row8 = tid >> 3;                        // 0..31
  const int koff = (((tid & 7) ^ (row8 & 7))) * 8;  // swizzled source chunk offset
  const int sw = r16 & 7;
  f32x4 acc[4][4] = {};
  for (int kk = kStart; kk < kEnd; kk += 64) {
    __syncthreads();
#pragma unroll
    for (int s = 0; s < 4; ++s)
      async16(Ab + (size_t)(s * 32 + row8) * K + kk + koff, (char*)sA + s * 4096 + tid * 16);
#pragma unroll
    for (int s = 0; s < 4; ++s)
      async16(Bb + (size_t)(s * 32 + row8) * K + kk + koff, (char*)sB + s * 4096 + tid * 16);
    __syncthreads();
#pragma unroll
    for (int h = 0; h < 2; ++h) {
      const int slot = ((h * 4 + quad) ^ sw) * 8;
      bf16x8 af[4], bfr[4];
#pragma unroll
      for (int i = 0; i < 4; ++i)
        af[i] = *(const bf16x8*)(sA + (wm * 64 + i * 16 + r16) * 64 + slot);
#pragma unroll
      for (int j = 0; j < 4; ++j)
        bfr[j] = *(const bf16x8*)(sB + (wn * 64 + j * 16 + r16) * 64 + slot);
#pragma unroll
      for (int i = 0; i < 4; ++i)
#pragma unroll
        for (int j = 0; j < 4; ++j)
          acc[i][j] = __builtin_amdgcn_mfma_f32_16x16x32_bf16(af[i], bfr[j], acc[i][j], 0, 0, 0);
    }
  }
  ushort* Pz = P + ((size_t)blockIdx.z * 4096 + r0) * 512 + c0;
#pragma unroll
  for (int i = 0; i < 4; ++i)
#pragma unroll
    for (int j = 0; j < 4; ++j)
#pragma unroll
      for (int g = 0; g < 4; ++g)
        Pz[(size_t)(wm * 64 + i * 16 + quad * 4 + g) * 512 + (wn * 64 + j * 16 + r16)] =
            f2bf(acc[i][j][g]);
}

// ------- 4. combine 7 split-K bf16 partials + b1 + BN1 + ReLU -> h1 bf16 -----------------
__global__ __launch_bounds__(256) void combine_kernel(const ushort* __restrict__ P,
                                                      const float* __restrict__ b1,
                                                      const float* __restrict__ g1,
                                                      const float* __restrict__ bt1,
                                                      const float* __restrict__ m1,
                                                      const float* __restrict__ v1,
                                                      ushort* __restrict__ h1) {
  size_t i = (size_t)blockIdx.x * 256 + threadIdx.x;  // exactly 4096*512
  int col = (int)(i & 511);
  float x = 0.f;
#pragma unroll
  for (int z = 0; z < 7; ++z) x += bf2f(P[i + (size_t)z * 2097152]);
  float s = g1[col] * rsqrtf(v1[col] + BN_EPS);
  float val = fmaxf((x + b1[col] - m1[col]) * s + bt1[col], 0.f);
  h1[i] = f2bf(val);
}

// ------- 5. GEMM2 (64x128 tile, BK=64) + b2 + BN2 + ReLU + group-of-8 max -> out ---------
__global__ __launch_bounds__(256) void gemm2_kernel(const ushort* __restrict__ A,
                                                    const ushort* __restrict__ B,
                                                    const float* __restrict__ b2,
                                                    const float* __restrict__ g2,
                                                    const float* __restrict__ bt2,
                                                    const float* __restrict__ m2,
                                                    const float* __restrict__ v2,
                                                    float* __restrict__ out) {
  constexpr int K = 512;
  __shared__ __align__(16) ushort sA[64 * 64];   // 8 KB
  __shared__ __align__(16) ushort sB[128 * 64];  // 16 KB
  __shared__ ushort st[64 * 128];                // post-activation tile for group-max
  const int tid = threadIdx.x;
  const int lane = tid & 63, wave = tid >> 6;
  const int wm = wave >> 1, wn = wave & 1;
  const int r16 = lane & 15, quad = lane >> 4;
  const int r0 = blockIdx.x * 64, c0 = blockIdx.y * 128;
  const ushort* Ab = A + (size_t)r0 * K;
  const ushort* Bb = B + (size_t)c0 * K;
  const int row8 = tid >> 3;
  const int koff = (((tid & 7) ^ (row8 & 7))) * 8;
  const int sw = r16 & 7;
  f32x4 acc[2][4] = {};
  for (int kk = 0; kk < K; kk += 64) {
    __syncthreads();
#pragma unroll
    for (int s = 0; s < 2; ++s)
      async16(Ab + (size_t)(s * 32 + row8) * K + kk + koff, (char*)sA + s * 4096 + tid * 16);
#pragma unroll
    for (int s = 0; s < 4; ++s)
      async16(Bb + (size_t)(s * 32 + row8) * K + kk + koff, (char*)sB + s * 4096 + tid * 16);
    __syncthreads();
#pragma unroll
    for (int h = 0; h < 2; ++h) {
      const int slot = ((h * 4 + quad) ^ sw) * 8;
      bf16x8 af[2], bfr[4];
#pragma unroll
      for (int i = 0; i < 2; ++i)
        af[i] = *(const bf16x8*)(sA + (wm * 32 + i * 16 + r16) * 64 + slot);
#pragma unroll
      for (int j = 0; j < 4; ++j)
        bfr[j] = *(const bf16x8*)(sB + (wn * 64 + j * 16 + r16) * 64 + slot);
#pragma unroll
      for (int i = 0; i < 2; ++i)
#pragma unroll
        for (int j = 0; j < 4; ++j)
          acc[i][j] = __builtin_amdgcn_mfma_f32_16x16x32_bf16(af[i], bfr[j], acc[i][j], 0, 0, 0);
    }
  }
  float ss[4], tt[4], bbv[4];
#pragma unroll
  for (int j = 0; j < 4; ++j) {
    int c = c0 + wn * 64 + j * 16 + r16;
    float s = g2[c] * rsqrtf(v2[c] + BN_EPS);
    ss[j] = s; tt[j] = bt2[c] - m2[c] * s; bbv[j] = b2[c];
  }
#pragma unroll
  for (int i = 0; i < 2; ++i)
#pragma unroll
    for (int j = 0; j < 4; ++j)
#pragma unroll
      for (int g = 0; g < 4; ++g) {
        int rr = wm * 32 + i * 16 + quad * 4 + g;
        int cc = wn * 64 + j * 16 + r16;
        float x = (acc[i][j][g] + bbv[j]) * ss[j] + tt[j];
        st[rr * 128 + cc] = f2bf(fmaxf(x, 0.f));
      }
  __syncthreads();
  for (int e = tid; e < 1024; e += 256) {
    int gg = e >> 7, cc = e & 127;
    float m = 0.f;  // relu output >= 0
#pragma unroll
    for (int k = 0; k < 8; ++k) m = fmaxf(m, bf2f(st[(gg * 8 + k) * 128 + cc]));
    out[(size_t)(r0 / 8 + gg) * 512 + c0 + cc] = m;
  }
}

extern "C" void kernel_launch(void* const* d_in, const int* in_sizes, int n_in,
                              void* d_out, int out_size, void* d_ws, size_t ws_size,
                              hipStream_t stream) {
  (void)in_sizes; (void)n_in; (void)out_size; (void)ws_size;
  const float* images = (const float*)d_in[0];
  const int* kf      = (const int*)d_in[1];
  const float* boxes = (const float*)d_in[2];
  const float* w1    = (const float*)d_in[3];
  const float* b1    = (const float*)d_in[4];
  const float* g1    = (const float*)d_in[5];
  const float* bt1   = (const float*)d_in[6];
  const float* m1    = (const float*)d_in[7];
  const float* v1    = (const float*)d_in[8];
  const float* w2    = (const float*)d_in[9];
  const float* b2    = (const float*)d_in[10];
  const float* g2    = (const float*)d_in[11];
  const float* bt2   = (const float*)d_in[12];
  const float* m2    = (const float*)d_in[13];
  const float* v2    = (const float*)d_in[14];
  float* out = (float*)d_out;

  char* ws = (char*)d_ws;
  // layout (bytes):  [ws_size = 400 MiB; imgTb eliminated in R14]
  //   A      @ 0          : 4096*12544*2 = 102,760,448
  //   w1b    @ 102,760,448: 512*12544*2  =  12,845,056
  //   w2b    @ 115,605,504: 512*512*2    =     524,288
  //   P      @ 116,129,792: 7*4096*512*2 = 29,360,128
  //   h1     @ 149,684,224: 4096*512*2   =   4,194,304
  //   perm   @ 168,558,592: 4096*4       =      16,384
  //   fstart @ 168,574,976: 65*4         =         260 (pad to 1024)
  //   widx   @ 168,576,000: 200704*4     =     802,816
  //   wts    @ 169,378,816: 200704*16    =   3,211,264  (16B aligned)
  ushort* Abuf  = (ushort*)(ws + 0);
  ushort* w1b   = (ushort*)(ws + 102760448);
  ushort* w2b   = (ushort*)(ws + 115605504);
  ushort* P     = (ushort*)(ws + 116129792);
  ushort* h1    = (ushort*)(ws + 149684224);
  int*    perm  = (int*)(ws + 168558592);
  int*    fstart= (int*)(ws + 168574976);
  uint*   widx  = (uint*)(ws + 168576000);
  float4* wtsp  = (float4*)(ws + 169378816);

  hipLaunchKernelGGL(prep_kernel, dim3(867), dim3(256), 0, stream,
                     w1, w1b, w2, w2b, kf, boxes, perm, fstart, widx, wtsp);
  hipLaunchKernelGGL(roi_fused_kernel, dim3(512), dim3(1024), 0, stream,
                     images, perm, fstart, widx, wtsp, Abuf);
  hipLaunchKernelGGL(gemm1_kernel, dim3(32, 4, 7), dim3(256), 0, stream, Abuf, w1b, P);
  hipLaunchKernelGGL(combine_kernel, dim3(8192), dim3(256), 0, stream, P, b1, g1, bt1, m1, v1, h1);
  hipLaunchKernelGGL(gemm2_kernel, dim3(64, 4), dim3(256), 0, stream, h1, w2b, b2, g2, bt2, m2, v2, out);
}

// Round 7
// 349.869 us; speedup vs baseline: 1.2186x; 1.1102x over previous
//
#include <hip/hip_runtime.h>

// NodeEncoder: RoIAlign -> FC1(12544->512)+BN+ReLU -> FC2(512->512)+BN+ReLU -> max over K=8
// F=64 C=256 H=W=40, N=512 K=8 (R=4096), ROI=7, HID=D=512
// NOTE: harness re-poisons 400MiB d_ws (~61us fill) + restores inputs (~45us) inside the
// timed region -> ~106us fixed overhead. Kernel budget is what we optimize.
//
// R16: R15's roi was latency-bound by BLOCK-serial roi loop (1.5 items/thread/roi, full
// dependent chain per roi). Restructure: one WAVE per roi (16 rois in flight/block),
// 24-25 independent inner iterations per wave -> pipelined. Load/LDS/write unchanged.
// Predicted roi_fused 156 -> 50-65us. Kill: >80us -> revert to R1 split structure.

typedef __bf16 bf16x8 __attribute__((ext_vector_type(8)));
typedef float f32x4 __attribute__((ext_vector_type(4)));
typedef ushort us8v __attribute__((ext_vector_type(8)));

#define BN_EPS 1e-3f

__device__ __forceinline__ ushort f2bf(float f) {
  union { float f; unsigned u; } v; v.f = f;
  unsigned r = (v.u + 0x7FFFu + ((v.u >> 16) & 1u)) >> 16;
  return (ushort)r;
}
__device__ __forceinline__ float bf2f(ushort b) {
  union { unsigned u; float f; } v; v.u = ((unsigned)b) << 16;
  return v.f;
}
__device__ __forceinline__ void async16(const void* g, void* l) {
  __builtin_amdgcn_global_load_lds((const __attribute__((address_space(1))) void*)g,
                                   (__attribute__((address_space(3))) void*)l, 16, 0, 0);
}

// ------- 1. prep: w1 conv (0..511) | w2 conv (512..767) | sort+fstart (768)
//            | RoI setup precompute (769..866: 98 blocks x 2048 items = 200,704 exactly)
__global__ __launch_bounds__(256) void prep_kernel(const float* __restrict__ w1,
                                                   ushort* __restrict__ w1b,
                                                   const float* __restrict__ w2,
                                                   ushort* __restrict__ w2b,
                                                   const int* __restrict__ kf,
                                                   const float* __restrict__ boxes,
                                                   int* __restrict__ perm,
                                                   int* __restrict__ fstart,
                                                   uint* __restrict__ widx,
                                                   float4* __restrict__ wts) {
  __shared__ __align__(16) char smem[25480];
  const int b = blockIdx.x;
  const int tid = threadIdx.x;
  if (b < 512) {
    // w1 [512][256][49] f32 -> w1b [512][49*256] bf16 (k = p*256+c); bf16 staging
    ushort* t = (ushort*)smem;  // [p][c], pitch 260, 49 rows = 25,480B
    const float* src = w1 + (size_t)b * 12544;
    for (int j = tid; j < 12544; j += 256) {
      int c = j / 49, p = j - c * 49;
      t[p * 260 + c] = f2bf(src[j]);
    }
    __syncthreads();
    ushort* dst = w1b + (size_t)b * 12544;
    for (int k0 = tid * 8; k0 < 12544; k0 += 2048) {
      int p = k0 >> 8, c = k0 & 255;
      ushort4 a = *(const ushort4*)(&t[p * 260 + c]);
      ushort4 d = *(const ushort4*)(&t[p * 260 + c + 4]);
      us8v o8;
      o8[0] = a.x; o8[1] = a.y; o8[2] = a.z; o8[3] = a.w;
      o8[4] = d.x; o8[5] = d.y; o8[6] = d.z; o8[7] = d.w;
      *(us8v*)(dst + k0) = o8;
    }
  } else if (b < 768) {
    // w2 [512][512] f32 -> bf16, float4 per thread
    const int o2 = b - 512;
    const size_t base = (size_t)o2 * 1024 + tid * 4;
    float4 vv = *(const float4*)(w2 + base);
    ushort4 o4;
    o4.x = f2bf(vv.x); o4.y = f2bf(vv.y); o4.z = f2bf(vv.z); o4.w = f2bf(vv.w);
    *(ushort4*)(w2b + base) = o4;
  } else if (b == 768) {
    // counting sort of RoIs by frame -> perm[4096], frame boundaries -> fstart[65]
    int* cnt = (int*)smem;
    int* base = cnt + 64;
    if (tid < 64) cnt[tid] = 0;
    __syncthreads();
    for (int r = tid; r < 4096; r += 256) atomicAdd(&cnt[kf[r]], 1);
    __syncthreads();
    if (tid == 0) {
      int acc = 0;
      for (int f = 0; f < 64; ++f) { base[f] = acc; fstart[f] = acc; acc += cnt[f]; }
      fstart[64] = acc;  // = 4096
    }
    __syncthreads();
    for (int r = tid; r < 4096; r += 256) {
      int p = atomicAdd(&base[kf[r]], 1);
      perm[p] = r;
    }
  } else {
    // RoI interp setup: for each (r, p) of 4096x49: packed corner idx + float4 weights
    const int i0 = (b - 769) * 2048 + tid * 8;
#pragma unroll
    for (int e = 0; e < 8; ++e) {
      const int idx = i0 + e;  // < 200,704 guaranteed (98*2048 exact)
      const int r = idx / 49, p = idx - r * 49;
      const int py = p / 7, px = p - py * 7;
      const float x1 = boxes[r * 4 + 0] * 40.f, y1 = boxes[r * 4 + 1] * 40.f;
      const float x2 = boxes[r * 4 + 2] * 40.f, y2 = boxes[r * 4 + 3] * 40.f;
      const float bw = (x2 - x1) * (1.f / 7.f), bh = (y2 - y1) * (1.f / 7.f);
      const float X = x1 + (px + 0.5f) * bw, Y = y1 + (py + 0.5f) * bh;
      const bool valid = (X > -1.f) && (X < 40.f) && (Y > -1.f) && (Y < 40.f);
      const float x = fminf(fmaxf(X, 0.f), 39.f), y = fminf(fmaxf(Y, 0.f), 39.f);
      const float x0f = floorf(x), y0f = floorf(y);
      const int x0 = (int)x0f, y0 = (int)y0f;
      const int x1i = min(x0 + 1, 39), y1i = min(y0 + 1, 39);
      const float lx = x - x0f, ly = y - y0f;
      const float vm = valid ? 1.f : 0.f;
      const uint o00 = (uint)(y0 * 40 + x0);
      const uint dx = (uint)(x1i - x0);        // 0 or 1
      const uint dyf = (uint)(y1i - y0);       // 0 or 1 (means +40)
      widx[idx] = o00 | (dx << 11) | (dyf << 12);
      wts[idx] = make_float4((1.f - ly) * (1.f - lx) * vm, (1.f - ly) * lx * vm,
                             ly * (1.f - lx) * vm, ly * lx * vm);
    }
  }
}

// ------- 2. fused transpose+RoIAlign -> A [4096][12544] bf16, k = (py*7+px)*256 + c -----
// block = (frame f, channel-group cg of 32): load images[f, cg*32.., :, :] f32 coalesced
// -> LDS bf16 [32][1604]. Then ONE WAVE PER ROI: wave w takes idx = s0+w, s0+w+16,...;
// lane = (ph, chl): p = ph, ph+2, ..., 48 -> 24-25 independent iterations (2 broadcast
// loads + 4 LDS u16 + 4 FMA each), fully pipelined. Writes = full 64-B sectors.
__global__ __launch_bounds__(1024) void roi_fused_kernel(const float* __restrict__ img,
                                                         const int* __restrict__ perm,
                                                         const int* __restrict__ fstart,
                                                         const uint* __restrict__ widx,
                                                         const float4* __restrict__ wts,
                                                         ushort* __restrict__ A) {
  __shared__ ushort lds[32 * 1604];  // 102,656 B
  const int tid = threadIdx.x;
  const int f = blockIdx.x >> 3, cg = blockIdx.x & 7;
  const float* src = img + (size_t)f * 409600 + (size_t)(cg * 32) * 1600;
  // load: 12800 float4 (=32ch x 400 quads) -> ushort4 stores (8B-aligned)
  for (int i = tid; i < 12800; i += 1024) {
    int ch = i / 400, pos = i - ch * 400;
    float4 v = *(const float4*)(src + (size_t)ch * 1600 + pos * 4);
    ushort4 o;
    o.x = f2bf(v.x); o.y = f2bf(v.y); o.z = f2bf(v.z); o.w = f2bf(v.w);
    *(ushort4*)(&lds[ch * 1604 + pos * 4]) = o;
  }
  __syncthreads();
  const int s0 = fstart[f], s1 = fstart[f + 1];
  const int wid = tid >> 6;        // wave 0..15
  const int lane = tid & 63;
  const int chl = lane & 31;       // channel within group
  const int ph = lane >> 5;        // 0/1: even/odd positions
  const ushort* lrow = &lds[chl * 1604];
  ushort* Abase = A + cg * 32 + chl;
  for (int idx = s0 + wid; idx < s1; idx += 16) {
    const int r = perm[idx];
    const uint* wip = widx + r * 49;
    const float4* wwp = wts + r * 49;
    ushort* outp = Abase + (size_t)r * 12544;
    for (int p = ph; p < 49; p += 2) {
      const uint pk = wip[p];          // broadcast across 32 lanes sharing p
      const float4 w = wwp[p];         // broadcast
      const int o00 = (int)(pk & 2047u);
      const int dx = (int)((pk >> 11) & 1u);
      const int dy = ((pk >> 12) & 1u) ? 40 : 0;
      const float a = bf2f(lrow[o00]);
      const float b = bf2f(lrow[o00 + dx]);
      const float c = bf2f(lrow[o00 + dy]);
      const float d = bf2f(lrow[o00 + dx + dy]);
      outp[p * 256] = f2bf(a * w.x + b * w.y + c * w.z + d * w.w);
    }
  }
}

// ------- 3. GEMM1: [4096,12544]x[512,12544]^T bf16, BK=64, split-K=7, bf16 partials ------
// __launch_bounds__(256,4): force <=128 unified regs/wave (64 acc AGPR + <=64 VGPR) so
// 4 blocks/CU fit (was 3 at 140 regs) -> more cross-block overlap of the barrier drain.
// LDS swizzle (BK=64, 8 chunks/row): slot s of row R holds global chunk s ^ (R&7).
__global__ __launch_bounds__(256, 4) void gemm1_kernel(const ushort* __restrict__ A,
                                                       const ushort* __restrict__ B,
                                                       ushort* __restrict__ P) {
  constexpr int K = 12544;
  constexpr int KS = 1792;  // = K/7, 28 iters of 64
  __shared__ __align__(16) ushort sA[128 * 64];  // 16 KB
  __shared__ __align__(16) ushort sB[128 * 64];  // 16 KB
  const int tid = threadIdx.x;
  const int lane = tid & 63, wave = tid >> 6;
  const int wm = wave >> 1, wn = wave & 1;
  const int r16 = lane & 15, quad = lane >> 4;
  const int r0 = blockIdx.x * 128, c0 = blockIdx.y * 128;
  const int kStart = blockIdx.z * KS, kEnd = kStart + KS;
  const ushort* Ab = A + (size_t)r0 * K;
  const ushort* Bb = B + (size_t)c0 * K;
  const int row8 = tid >> 3;                        // 0..31
  const int koff = (((tid & 7) ^ (row8 & 7))) * 8;  // swizzled source chunk offset
  const int sw = r16 & 7;
  f32x4 acc[4][4] = {};
  for (int kk = kStart; kk < kEnd; kk += 64) {
    __syncthreads();
#pragma unroll
    for (int s = 0; s < 4; ++s)
      async16(Ab + (size_t)(s * 32 + row8) * K + kk + koff, (char*)sA + s * 4096 + tid * 16);
#pragma unroll
    for (int s = 0; s < 4; ++s)
      async16(Bb + (size_t)(s * 32 + row8) * K + kk + koff, (char*)sB + s * 4096 + tid * 16);
    __syncthreads();
#pragma unroll
    for (int h = 0; h < 2; ++h) {
      const int slot = ((h * 4 + quad) ^ sw) * 8;
      bf16x8 af[4], bfr[4];
#pragma unroll
      for (int i = 0; i < 4; ++i)
        af[i] = *(const bf16x8*)(sA + (wm * 64 + i * 16 + r16) * 64 + slot);
#pragma unroll
      for (int j = 0; j < 4; ++j)
        bfr[j] = *(const bf16x8*)(sB + (wn * 64 + j * 16 + r16) * 64 + slot);
#pragma unroll
      for (int i = 0; i < 4; ++i)
#pragma unroll
        for (int j = 0; j < 4; ++j)
          acc[i][j] = __builtin_amdgcn_mfma_f32_16x16x32_bf16(af[i], bfr[j], acc[i][j], 0, 0, 0);
    }
  }
  ushort* Pz = P + ((size_t)blockIdx.z * 4096 + r0) * 512 + c0;
#pragma unroll
  for (int i = 0; i < 4; ++i)
#pragma unroll
    for (int j = 0; j < 4; ++j)
#pragma unroll
      for (int g = 0; g < 4; ++g)
        Pz[(size_t)(wm * 64 + i * 16 + quad * 4 + g) * 512 + (wn * 64 + j * 16 + r16)] =
            f2bf(acc[i][j][g]);
}

// ------- 4. combine 7 split-K bf16 partials + b1 + BN1 + ReLU -> h1 bf16 -----------------
__global__ __launch_bounds__(256) void combine_kernel(const ushort* __restrict__ P,
                                                      const float* __restrict__ b1,
                                                      const float* __restrict__ g1,
                                                      const float* __restrict__ bt1,
                                                      const float* __restrict__ m1,
                                                      const float* __restrict__ v1,
                                                      ushort* __restrict__ h1) {
  size_t i = (size_t)blockIdx.x * 256 + threadIdx.x;  // exactly 4096*512
  int col = (int)(i & 511);
  float x = 0.f;
#pragma unroll
  for (int z = 0; z < 7; ++z) x += bf2f(P[i + (size_t)z * 2097152]);
  float s = g1[col] * rsqrtf(v1[col] + BN_EPS);
  float val = fmaxf((x + b1[col] - m1[col]) * s + bt1[col], 0.f);
  h1[i] = f2bf(val);
}

// ------- 5. GEMM2 (64x128 tile, BK=64) + b2 + BN2 + ReLU + group-of-8 max -> out ---------
__global__ __launch_bounds__(256) void gemm2_kernel(const ushort* __restrict__ A,
                                                    const ushort* __restrict__ B,
                                                    const float* __restrict__ b2,
                                                    const float* __restrict__ g2,
                                                    const float* __restrict__ bt2,
                                                    const float* __restrict__ m2,
                                                    const float* __restrict__ v2,
                                                    float* __restrict__ out) {
  constexpr int K = 512;
  __shared__ __align__(16) ushort sA[64 * 64];   // 8 KB
  __shared__ __align__(16) ushort sB[128 * 64];  // 16 KB
  __shared__ ushort st[64 * 128];                // post-activation tile for group-max
  const int tid = threadIdx.x;
  const int lane = tid & 63, wave = tid >> 6;
  const int wm = wave >> 1, wn = wave & 1;
  const int r16 = lane & 15, quad = lane >> 4;
  const int r0 = blockIdx.x * 64, c0 = blockIdx.y * 128;
  const ushort* Ab = A + (size_t)r0 * K;
  const ushort* Bb = B + (size_t)c0 * K;
  const int row8 = tid >> 3;
  const int koff = (((tid & 7) ^ (row8 & 7))) * 8;
  const int sw = r16 & 7;
  f32x4 acc[2][4] = {};
  for (int kk = 0; kk < K; kk += 64) {
    __syncthreads();
#pragma unroll
    for (int s = 0; s < 2; ++s)
      async16(Ab + (size_t)(s * 32 + row8) * K + kk + koff, (char*)sA + s * 4096 + tid * 16);
#pragma unroll
    for (int s = 0; s < 4; ++s)
      async16(Bb + (size_t)(s * 32 + row8) * K + kk + koff, (char*)sB + s * 4096 + tid * 16);
    __syncthreads();
#pragma unroll
    for (int h = 0; h < 2; ++h) {
      const int slot = ((h * 4 + quad) ^ sw) * 8;
      bf16x8 af[2], bfr[4];
#pragma unroll
      for (int i = 0; i < 2; ++i)
        af[i] = *(const bf16x8*)(sA + (wm * 32 + i * 16 + r16) * 64 + slot);
#pragma unroll
      for (int j = 0; j < 4; ++j)
        bfr[j] = *(const bf16x8*)(sB + (wn * 64 + j * 16 + r16) * 64 + slot);
#pragma unroll
      for (int i = 0; i < 2; ++i)
#pragma unroll
        for (int j = 0; j < 4; ++j)
          acc[i][j] = __builtin_amdgcn_mfma_f32_16x16x32_bf16(af[i], bfr[j], acc[i][j], 0, 0, 0);
    }
  }
  float ss[4], tt[4], bbv[4];
#pragma unroll
  for (int j = 0; j < 4; ++j) {
    int c = c0 + wn * 64 + j * 16 + r16;
    float s = g2[c] * rsqrtf(v2[c] + BN_EPS);
    ss[j] = s; tt[j] = bt2[c] - m2[c] * s; bbv[j] = b2[c];
  }
#pragma unroll
  for (int i = 0; i < 2; ++i)
#pragma unroll
    for (int j = 0; j < 4; ++j)
#pragma unroll
      for (int g = 0; g < 4; ++g) {
        int rr = wm * 32 + i * 16 + quad * 4 + g;
        int cc = wn * 64 + j * 16 + r16;
        float x = (acc[i][j][g] + bbv[j]) * ss[j] + tt[j];
        st[rr * 128 + cc] = f2bf(fmaxf(x, 0.f));
      }
  __syncthreads();
  for (int e = tid; e < 1024; e += 256) {
    int gg = e >> 7, cc = e & 127;
    float m = 0.f;  // relu output >= 0
#pragma unroll
    for (int k = 0; k < 8; ++k) m = fmaxf(m, bf2f(st[(gg * 8 + k) * 128 + cc]));
    out[(size_t)(r0 / 8 + gg) * 512 + c0 + cc] = m;
  }
}

extern "C" void kernel_launch(void* const* d_in, const int* in_sizes, int n_in,
                              void* d_out, int out_size, void* d_ws, size_t ws_size,
                              hipStream_t stream) {
  (void)in_sizes; (void)n_in; (void)out_size; (void)ws_size;
  const float* images = (const float*)d_in[0];
  const int* kf      = (const int*)d_in[1];
  const float* boxes = (const float*)d_in[2];
  const float* w1    = (const float*)d_in[3];
  const float* b1    = (const float*)d_in[4];
  const float* g1    = (const float*)d_in[5];
  const float* bt1   = (const float*)d_in[6];
  const float* m1    = (const float*)d_in[7];
  const float* v1    = (const float*)d_in[8];
  const float* w2    = (const float*)d_in[9];
  const float* b2    = (const float*)d_in[10];
  const float* g2    = (const float*)d_in[11];
  const float* bt2   = (const float*)d_in[12];
  const float* m2    = (const float*)d_in[13];
  const float* v2    = (const float*)d_in[14];
  float* out = (float*)d_out;

  char* ws = (char*)d_ws;
  // layout (bytes):  [ws_size = 400 MiB; imgTb eliminated in R14]
  //   A      @ 0          : 4096*12544*2 = 102,760,448
  //   w1b    @ 102,760,448: 512*12544*2  =  12,845,056
  //   w2b    @ 115,605,504: 512*512*2    =     524,288
  //   P      @ 116,129,792: 7*4096*512*2 = 29,360,128
  //   h1     @ 149,684,224: 4096*512*2   =   4,194,304
  //   perm   @ 168,558,592: 4096*4       =      16,384
  //   fstart @ 168,574,976: 65*4         =         260 (pad to 1024)
  //   widx   @ 168,576,000: 200704*4     =     802,816
  //   wts    @ 169,378,816: 200704*16    =   3,211,264  (16B aligned)
  ushort* Abuf  = (ushort*)(ws + 0);
  ushort* w1b   = (ushort*)(ws + 102760448);
  ushort* w2b   = (ushort*)(ws + 115605504);
  ushort* P     = (ushort*)(ws + 116129792);
  ushort* h1    = (ushort*)(ws + 149684224);
  int*    perm  = (int*)(ws + 168558592);
  int*    fstart= (int*)(ws + 168574976);
  uint*   widx  = (uint*)(ws + 168576000);
  float4* wtsp  = (float4*)(ws + 169378816);

  hipLaunchKernelGGL(prep_kernel, dim3(867), dim3(256), 0, stream,
                     w1, w1b, w2, w2b, kf, boxes, perm, fstart, widx, wtsp);
  hipLaunchKernelGGL(roi_fused_kernel, dim3(512), dim3(1024), 0, stream,
                     images, perm, fstart, widx, wtsp, Abuf);
  hipLaunchKernelGGL(gemm1_kernel, dim3(32, 4, 7), dim3(256), 0, stream, Abuf, w1b, P);
  hipLaunchKernelGGL(combine_kernel, dim3(8192), dim3(256), 0, stream, P, b1, g1, bt1, m1, v1, h1);
  hipLaunchKernelGGL(gemm2_kernel, dim3(64, 4), dim3(256), 0, stream, h1, w2b, b2, g2, bt2, m2, v2, out);
}

// Round 9
// 309.612 us; speedup vs baseline: 1.3770x; 1.1300x over previous
//
#include <hip/hip_runtime.h>

// NodeEncoder: RoIAlign -> FC1(12544->512)+BN+ReLU -> FC2(512->512)+BN+ReLU -> max over K=8
// F=64 C=256 H=W=40, N=512 K=8 (R=4096), ROI=7, HID=D=512
// NOTE: harness re-poisons 400MiB d_ws (~61us fill) + restores inputs (~45us) inside the
// timed region -> ~106us fixed overhead. Kernel budget is what we optimize.
//
// R18 = R17 resubmitted (R17 bench was GPUAcquisitionTimeout; never measured).
// R17: fused-roi excursion (R14-R16) bottomed at 117us vs 103us for the split
// transpose+gather pair -> kill criterion fired; reverted to R12-measured structure.
// Delta vs R12: combine_kernel vectorized (us8v: 7x16B loads + 16B store, was 7 scalar
// u16 loads). Predicted: prep ~68-70, roi ~35, combine 6->~3, total ~302-306.

typedef __bf16 bf16x8 __attribute__((ext_vector_type(8)));
typedef float f32x4 __attribute__((ext_vector_type(4)));
typedef ushort us8v __attribute__((ext_vector_type(8)));

#define BN_EPS 1e-3f

__device__ __forceinline__ ushort f2bf(float f) {
  union { float f; unsigned u; } v; v.f = f;
  unsigned r = (v.u + 0x7FFFu + ((v.u >> 16) & 1u)) >> 16;
  return (ushort)r;
}
__device__ __forceinline__ float bf2f(ushort b) {
  union { unsigned u; float f; } v; v.u = ((unsigned)b) << 16;
  return v.f;
}
__device__ __forceinline__ void async16(const void* g, void* l) {
  __builtin_amdgcn_global_load_lds((const __attribute__((address_space(1))) void*)g,
                                   (__attribute__((address_space(3))) void*)l, 16, 0, 0);
}

// ------- 1. prep: interleaved roles. 3969 blocks total:
//   b < 3845: b%5<4 -> transpose tIdx=(b/5)*4+b%5 ; b%5==4 -> other oIdx=b/5
//   b >= 3845: transpose tIdx = 3076 + (b-3845)
//   other: oIdx 0..511 = w1 conv | 512..767 = w2 conv (float4) | 768 = RoI frame-sort
// Union smem 25,480B: transpose 16,640B | w1 tile 25,480B | sort 512B -> 6 blocks/CU.
__global__ __launch_bounds__(256, 6) void prep_kernel(const float* __restrict__ img,
                                                      ushort* __restrict__ imgTb,
                                                      const float* __restrict__ w1,
                                                      ushort* __restrict__ w1b,
                                                      const float* __restrict__ w2,
                                                      ushort* __restrict__ w2b,
                                                      const int* __restrict__ kf,
                                                      int* __restrict__ perm) {
  __shared__ __align__(16) char smem[25480];
  const int b = blockIdx.x;
  const int tid = threadIdx.x;
  int tIdx = -1, oIdx = -1;
  if (b < 3845) {
    int q = b / 5, r = b - q * 5;
    if (r < 4) tIdx = q * 4 + r; else oIdx = q;
  } else {
    tIdx = 3076 + (b - 3845);
  }
  if (tIdx >= 0) {
    // images [64,256,40,40] f32 -> imgTb [64,40,40,256] bf16; 256ch x 32px tile
    ushort* lds = (ushort*)smem;  // [pixel][channel], pitch 260, 32 rows = 16,640B
    const int f = tIdx / 50, p0 = (tIdx % 50) * 32;
    const float* src = img + (size_t)f * 409600 + p0;
    float4 v[2][4];
#pragma unroll
    for (int m = 0; m < 2; ++m) {
      int g = m * 256 + tid;
      int cg = g >> 3;  // channel group (4 ch), 0..63
      int pg = g & 7;   // pixel group (4 px), 0..7
#pragma unroll
      for (int j = 0; j < 4; ++j)
        v[m][j] = *(const float4*)(src + (size_t)(cg * 4 + j) * 1600 + pg * 4);
    }
#pragma unroll
    for (int m = 0; m < 2; ++m) {
      int g = m * 256 + tid;
      int cg = g >> 3;
      int pg = g & 7;
#pragma unroll
      for (int i = 0; i < 4; ++i) {
        ushort4 o;
        o.x = f2bf((&v[m][0].x)[i]);
        o.y = f2bf((&v[m][1].x)[i]);
        o.z = f2bf((&v[m][2].x)[i]);
        o.w = f2bf((&v[m][3].x)[i]);
        *(ushort4*)(&lds[(pg * 4 + i) * 260 + cg * 4]) = o;
      }
    }
    __syncthreads();
    ushort* dst = imgTb + ((size_t)f * 1600 + p0) * 256;
#pragma unroll
    for (int q = 0; q < 4; ++q) {
      int p = q * 8 + (tid >> 5);  // 0..31
      int cg8 = tid & 31;
      ushort4 a = *(const ushort4*)(&lds[p * 260 + cg8 * 8]);
      ushort4 c = *(const ushort4*)(&lds[p * 260 + cg8 * 8 + 4]);
      us8v o;
      o[0] = a.x; o[1] = a.y; o[2] = a.z; o[3] = a.w;
      o[4] = c.x; o[5] = c.y; o[6] = c.z; o[7] = c.w;
      *(us8v*)(dst + (size_t)p * 256 + cg8 * 8) = o;
    }
  } else if (oIdx < 512) {
    // w1 [512][256][49] f32 -> w1b [512][49*256] bf16 (k = p*256+c); bf16 staging
    ushort* t = (ushort*)smem;  // [p][c], pitch 260, 49 rows = 25,480B
    const int o = oIdx;
    const float* src = w1 + (size_t)o * 12544;
    for (int j = tid; j < 12544; j += 256) {
      int c = j / 49, p = j - c * 49;
      t[p * 260 + c] = f2bf(src[j]);
    }
    __syncthreads();
    ushort* dst = w1b + (size_t)o * 12544;
    for (int k0 = tid * 8; k0 < 12544; k0 += 2048) {
      int p = k0 >> 8, c = k0 & 255;
      ushort4 a = *(const ushort4*)(&t[p * 260 + c]);
      ushort4 d = *(const ushort4*)(&t[p * 260 + c + 4]);
      us8v o8;
      o8[0] = a.x; o8[1] = a.y; o8[2] = a.z; o8[3] = a.w;
      o8[4] = d.x; o8[5] = d.y; o8[6] = d.z; o8[7] = d.w;
      *(us8v*)(dst + k0) = o8;
    }
  } else if (oIdx < 768) {
    // w2 [512][512] f32 -> bf16, float4 per thread
    const int o2 = oIdx - 512;
    const size_t base = (size_t)o2 * 1024 + tid * 4;
    float4 vv = *(const float4*)(w2 + base);
    ushort4 o4;
    o4.x = f2bf(vv.x); o4.y = f2bf(vv.y); o4.z = f2bf(vv.z); o4.w = f2bf(vv.w);
    *(ushort4*)(w2b + base) = o4;
  } else {
    // counting sort of RoIs by frame -> perm[4096]
    int* cnt = (int*)smem;
    int* base = cnt + 64;
    if (tid < 64) cnt[tid] = 0;
    __syncthreads();
    for (int r = tid; r < 4096; r += 256) atomicAdd(&cnt[kf[r]], 1);
    __syncthreads();
    if (tid == 0) {
      int acc = 0;
      for (int f = 0; f < 64; ++f) { base[f] = acc; acc += cnt[f]; }
    }
    __syncthreads();
    for (int r = tid; r < 4096; r += 256) {
      int p = atomicAdd(&base[kf[r]], 1);
      perm[p] = r;
    }
  }
}

// ------- 2. RoIAlign (bf16 image) -> A [4096][12544] bf16, k = (py*7+px)*256 + c ---------
// XCD-locality: perm is frame-sorted; blocks with same (blockIdx&7) share an XCD and walk
// ~8 consecutive frames -> gathers stay in that XCD's 4MB L2. [R9: -16us validated]
__global__ __launch_bounds__(256) void roi_kernel(const ushort* __restrict__ imgTb,
                                                  const int* __restrict__ kf,
                                                  const float* __restrict__ boxes,
                                                  const int* __restrict__ perm,
                                                  ushort* __restrict__ A) {
  __shared__ int sy0[49], sx0[49], sy1[49], sx1[49];
  __shared__ float sw00[49], sw01[49], sw10[49], sw11[49];
  __shared__ int sf, sr;
  const int tid = threadIdx.x;
  if (tid == 0) {
    int r = perm[((blockIdx.x & 7) << 9) | (blockIdx.x >> 3)];
    sr = r;
    sf = kf[r];
  }
  __syncthreads();
  const int r = sr;
  if (tid < 49) {
    int py = tid / 7, px = tid % 7;
    float x1 = boxes[r * 4 + 0] * 40.f, y1 = boxes[r * 4 + 1] * 40.f;
    float x2 = boxes[r * 4 + 2] * 40.f, y2 = boxes[r * 4 + 3] * 40.f;
    float bw = (x2 - x1) * (1.f / 7.f), bh = (y2 - y1) * (1.f / 7.f);
    float X = x1 + (px + 0.5f) * bw, Y = y1 + (py + 0.5f) * bh;
    bool valid = (X > -1.f) && (X < 40.f) && (Y > -1.f) && (Y < 40.f);
    float x = fminf(fmaxf(X, 0.f), 39.f), y = fminf(fmaxf(Y, 0.f), 39.f);
    float x0f = floorf(x), y0f = floorf(y);
    int x0 = (int)x0f, y0 = (int)y0f;
    int x1i = min(x0 + 1, 39), y1i = min(y0 + 1, 39);
    float lx = x - x0f, ly = y - y0f;
    float vm = valid ? 1.f : 0.f;
    sx0[tid] = x0; sy0[tid] = y0; sx1[tid] = x1i; sy1[tid] = y1i;
    sw00[tid] = (1.f - ly) * (1.f - lx) * vm;
    sw01[tid] = (1.f - ly) * lx * vm;
    sw10[tid] = ly * (1.f - lx) * vm;
    sw11[tid] = ly * lx * vm;
  }
  __syncthreads();
  const int c8 = (tid & 31) * 8;
  const int pq = tid >> 5;
  const ushort* base = imgTb + (size_t)sf * 409600 + c8;
  ushort* outp = A + (size_t)r * 12544 + c8;
  for (int p = pq; p < 49; p += 8) {
    const us8v a = *(const us8v*)(base + (size_t)(sy0[p] * 40 + sx0[p]) * 256);
    const us8v b = *(const us8v*)(base + (size_t)(sy0[p] * 40 + sx1[p]) * 256);
    const us8v c = *(const us8v*)(base + (size_t)(sy1[p] * 40 + sx0[p]) * 256);
    const us8v d = *(const us8v*)(base + (size_t)(sy1[p] * 40 + sx1[p]) * 256);
    float w00 = sw00[p], w01 = sw01[p], w10 = sw10[p], w11 = sw11[p];
    us8v o;
#pragma unroll
    for (int k = 0; k < 8; ++k)
      o[k] = f2bf(bf2f(a[k]) * w00 + bf2f(b[k]) * w01 + bf2f(c[k]) * w10 + bf2f(d[k]) * w11);
    *(us8v*)(outp + (size_t)p * 256) = o;
  }
}

// ------- 3. GEMM1: [4096,12544]x[512,12544]^T bf16, BK=64, split-K=7, bf16 partials ------
// __launch_bounds__(256,4): force <=128 unified regs/wave (64 acc AGPR + <=64 VGPR) so
// 4 blocks/CU fit (was 3 at 140 regs) -> more cross-block overlap of the barrier drain.
// LDS swizzle (BK=64, 8 chunks/row): slot s of row R holds global chunk s ^ (R&7).
__global__ __launch_bounds__(256, 4) void gemm1_kernel(const ushort* __restrict__ A,
                                                       const ushort* __restrict__ B,
                                                       ushort* __restrict__ P) {
  constexpr int K = 12544;
  constexpr int KS = 1792;  // = K/7, 28 iters of 64
  __shared__ __align__(16) ushort sA[128 * 64];  // 16 KB
  __shared__ __align__(16) ushort sB[128 * 64];  // 16 KB
  const int tid = threadIdx.x;
  const int lane = tid & 63, wave = tid >> 6;
  const int wm = wave >> 1, wn = wave & 1;
  const int r16 = lane & 15, quad = lane >> 4;
  const int r0 = blockIdx.x * 128, c0 = blockIdx.y * 128;
  const int kStart = blockIdx.z * KS, kEnd = kStart + KS;
  const ushort* Ab = A + (size_t)r0 * K;
  const ushort* Bb = B + (size_t)c0 * K;
  const int row8 = tid >> 3;                        // 0..31
  const int koff = (((tid & 7) ^ (row8 & 7))) * 8;  // swizzled source chunk offset
  const int sw = r16 & 7;
  f32x4 acc[4][4] = {};
  for (int kk = kStart; kk < kEnd; kk += 64) {
    __syncthreads();
#pragma unroll
    for (int s = 0; s < 4; ++s)
      async16(Ab + (size_t)(s * 32 + row8) * K + kk + koff, (char*)sA + s * 4096 + tid * 16);
#pragma unroll
    for (int s = 0; s < 4; ++s)
      async16(Bb + (size_t)(s * 32 + row8) * K + kk + koff, (char*)sB + s * 4096 + tid * 16);
    __syncthreads();
#pragma unroll
    for (int h = 0; h < 2; ++h) {
      const int slot = ((h * 4 + quad) ^ sw) * 8;
      bf16x8 af[4], bfr[4];
#pragma unroll
      for (int i = 0; i < 4; ++i)
        af[i] = *(const bf16x8*)(sA + (wm * 64 + i * 16 + r16) * 64 + slot);
#pragma unroll
      for (int j = 0; j < 4; ++j)
        bfr[j] = *(const bf16x8*)(sB + (wn * 64 + j * 16 + r16) * 64 + slot);
#pragma unroll
      for (int i = 0; i < 4; ++i)
#pragma unroll
        for (int j = 0; j < 4; ++j)
          acc[i][j] = __builtin_amdgcn_mfma_f32_16x16x32_bf16(af[i], bfr[j], acc[i][j], 0, 0, 0);
    }
  }
  ushort* Pz = P + ((size_t)blockIdx.z * 4096 + r0) * 512 + c0;
#pragma unroll
  for (int i = 0; i < 4; ++i)
#pragma unroll
    for (int j = 0; j < 4; ++j)
#pragma unroll
      for (int g = 0; g < 4; ++g)
        Pz[(size_t)(wm * 64 + i * 16 + quad * 4 + g) * 512 + (wn * 64 + j * 16 + r16)] =
            f2bf(acc[i][j][g]);
}

// ------- 4. combine 7 split-K bf16 partials + b1 + BN1 + ReLU -> h1 bf16 -----------------
// R17: vectorized us8v (was scalar u16 x7 loads + u16 store). 1024 blocks x 256 thr x 8.
__global__ __launch_bounds__(256) void combine_kernel(const ushort* __restrict__ P,
                                                      const float* __restrict__ b1,
                                                      const float* __restrict__ g1,
                                                      const float* __restrict__ bt1,
                                                      const float* __restrict__ m1,
                                                      const float* __restrict__ v1,
                                                      ushort* __restrict__ h1) {
  const size_t i0 = ((size_t)blockIdx.x * 256 + threadIdx.x) * 8;  // 1024*256*8 = 4096*512
  const int col = (int)(i0 & 511);  // 8-aligned, no row crossing
  float x[8] = {};
#pragma unroll
  for (int z = 0; z < 7; ++z) {
    us8v pv = *(const us8v*)(P + i0 + (size_t)z * 2097152);
#pragma unroll
    for (int e = 0; e < 8; ++e) x[e] += bf2f(pv[e]);
  }
  us8v o;
#pragma unroll
  for (int e = 0; e < 8; ++e) {
    int c = col + e;
    float s = g1[c] * rsqrtf(v1[c] + BN_EPS);
    o[e] = f2bf(fmaxf((x[e] + b1[c] - m1[c]) * s + bt1[c], 0.f));
  }
  *(us8v*)(h1 + i0) = o;
}

// ------- 5. GEMM2 (64x128 tile, BK=64) + b2 + BN2 + ReLU + group-of-8 max -> out ---------
__global__ __launch_bounds__(256) void gemm2_kernel(const ushort* __restrict__ A,
                                                    const ushort* __restrict__ B,
                                                    const float* __restrict__ b2,
                                                    const float* __restrict__ g2,
                                                    const float* __restrict__ bt2,
                                                    const float* __restrict__ m2,
                                                    const float* __restrict__ v2,
                                                    float* __restrict__ out) {
  constexpr int K = 512;
  __shared__ __align__(16) ushort sA[64 * 64];   // 8 KB
  __shared__ __align__(16) ushort sB[128 * 64];  // 16 KB
  __shared__ ushort st[64 * 128];                // post-activation tile for group-max
  const int tid = threadIdx.x;
  const int lane = tid & 63, wave = tid >> 6;
  const int wm = wave >> 1, wn = wave & 1;
  const int r16 = lane & 15, quad = lane >> 4;
  const int r0 = blockIdx.x * 64, c0 = blockIdx.y * 128;
  const ushort* Ab = A + (size_t)r0 * K;
  const ushort* Bb = B + (size_t)c0 * K;
  const int row8 = tid >> 3;
  const int koff = (((tid & 7) ^ (row8 & 7))) * 8;
  const int sw = r16 & 7;
  f32x4 acc[2][4] = {};
  for (int kk = 0; kk < K; kk += 64) {
    __syncthreads();
#pragma unroll
    for (int s = 0; s < 2; ++s)
      async16(Ab + (size_t)(s * 32 + row8) * K + kk + koff, (char*)sA + s * 4096 + tid * 16);
#pragma unroll
    for (int s = 0; s < 4; ++s)
      async16(Bb + (size_t)(s * 32 + row8) * K + kk + koff, (char*)sB + s * 4096 + tid * 16);
    __syncthreads();
#pragma unroll
    for (int h = 0; h < 2; ++h) {
      const int slot = ((h * 4 + quad) ^ sw) * 8;
      bf16x8 af[2], bfr[4];
#pragma unroll
      for (int i = 0; i < 2; ++i)
        af[i] = *(const bf16x8*)(sA + (wm * 32 + i * 16 + r16) * 64 + slot);
#pragma unroll
      for (int j = 0; j < 4; ++j)
        bfr[j] = *(const bf16x8*)(sB + (wn * 64 + j * 16 + r16) * 64 + slot);
#pragma unroll
      for (int i = 0; i < 2; ++i)
#pragma unroll
        for (int j = 0; j < 4; ++j)
          acc[i][j] = __builtin_amdgcn_mfma_f32_16x16x32_bf16(af[i], bfr[j], acc[i][j], 0, 0, 0);
    }
  }
  float ss[4], tt[4], bbv[4];
#pragma unroll
  for (int j = 0; j < 4; ++j) {
    int c = c0 + wn * 64 + j * 16 + r16;
    float s = g2[c] * rsqrtf(v2[c] + BN_EPS);
    ss[j] = s; tt[j] = bt2[c] - m2[c] * s; bbv[j] = b2[c];
  }
#pragma unroll
  for (int i = 0; i < 2; ++i)
#pragma unroll
    for (int j = 0; j < 4; ++j)
#pragma unroll
      for (int g = 0; g < 4; ++g) {
        int rr = wm * 32 + i * 16 + quad * 4 + g;
        int cc = wn * 64 + j * 16 + r16;
        float x = (acc[i][j][g] + bbv[j]) * ss[j] + tt[j];
        st[rr * 128 + cc] = f2bf(fmaxf(x, 0.f));
      }
  __syncthreads();
  for (int e = tid; e < 1024; e += 256) {
    int gg = e >> 7, cc = e & 127;
    float m = 0.f;  // relu output >= 0
#pragma unroll
    for (int k = 0; k < 8; ++k) m = fmaxf(m, bf2f(st[(gg * 8 + k) * 128 + cc]));
    out[(size_t)(r0 / 8 + gg) * 512 + c0 + cc] = m;
  }
}

extern "C" void kernel_launch(void* const* d_in, const int* in_sizes, int n_in,
                              void* d_out, int out_size, void* d_ws, size_t ws_size,
                              hipStream_t stream) {
  (void)in_sizes; (void)n_in; (void)out_size; (void)ws_size;
  const float* images = (const float*)d_in[0];
  const int* kf      = (const int*)d_in[1];
  const float* boxes = (const float*)d_in[2];
  const float* w1    = (const float*)d_in[3];
  const float* b1    = (const float*)d_in[4];
  const float* g1    = (const float*)d_in[5];
  const float* bt1   = (const float*)d_in[6];
  const float* m1    = (const float*)d_in[7];
  const float* v1    = (const float*)d_in[8];
  const float* w2    = (const float*)d_in[9];
  const float* b2    = (const float*)d_in[10];
  const float* g2    = (const float*)d_in[11];
  const float* bt2   = (const float*)d_in[12];
  const float* m2    = (const float*)d_in[13];
  const float* v2    = (const float*)d_in[14];
  float* out = (float*)d_out;

  char* ws = (char*)d_ws;
  // layout (bytes):  [ws_size >= 221 MB proven earlier]
  //   A     @ 0          : 4096*12544*2 = 102,760,448
  //   w1b   @ 102,760,448: 512*12544*2  =  12,845,056
  //   w2b   @ 115,605,504: 512*512*2    =     524,288
  //   imgTb @ 116,129,792: 64*1600*256*2 = 52,428,800 -> ends 168,558,592 (dead after roi)
  //   P     @ 116,129,792: 7*4096*512*2 = 29,360,128  (aliases imgTb head; written post-roi)
  //   h1    @ 149,684,224: 4096*512*2   =  4,194,304  (aliases imgTb mid; written post-roi)
  //   perm  @ 168,558,592: 4096*4       =      16,384 (strictly after imgTb end!)
  ushort* Abuf  = (ushort*)(ws + 0);
  ushort* w1b   = (ushort*)(ws + 102760448);
  ushort* w2b   = (ushort*)(ws + 115605504);
  ushort* imgTb = (ushort*)(ws + 116129792);
  ushort* P     = (ushort*)(ws + 116129792);
  ushort* h1    = (ushort*)(ws + 149684224);
  int*    perm  = (int*)(ws + 168558592);

  hipLaunchKernelGGL(prep_kernel, dim3(3969), dim3(256), 0, stream,
                     images, imgTb, w1, w1b, w2, w2b, kf, perm);
  hipLaunchKernelGGL(roi_kernel, dim3(4096), dim3(256), 0, stream, imgTb, kf, boxes, perm, Abuf);
  hipLaunchKernelGGL(gemm1_kernel, dim3(32, 4, 7), dim3(256), 0, stream, Abuf, w1b, P);
  hipLaunchKernelGGL(combine_kernel, dim3(1024), dim3(256), 0, stream, P, b1, g1, bt1, m1, v1, h1);
  hipLaunchKernelGGL(gemm2_kernel, dim3(64, 4), dim3(256), 0, stream, h1, w2b, b2, g2, bt2, m2, v2, out);
}

// Round 12
// 301.754 us; speedup vs baseline: 1.4129x; 1.0260x over previous
//
#include <hip/hip_runtime.h>

// NodeEncoder: RoIAlign -> FC1(12544->512)+BN+ReLU -> FC2(512->512)+BN+ReLU -> max over K=8
// F=64 C=256 H=W=40, N=512 K=8 (R=4096), ROI=7, HID=D=512
// NOTE: harness re-poisons 400MiB d_ws (~61us fill) + restores inputs (~45us) inside the
// timed region -> ~106us fixed overhead. prep (~68us @1.9TB/s) is floored by the dirty-L3
// writeback drain of that poison (roi right after runs at 4.3TB/s) -> structural, accept.
//
// R21 = R19 resubmitted twice (R19/R20 benches were GPUAcquisitionTimeout; never run).
// R19: gemm1 256x256 deep-pipelined port (T3+T4): grid (16,2,7)=224 blocks, 512thr/8
// waves, 1 blk/CU. A dbuf 64KB + B TRIPLE buf 96KB = 160KB LDS -> counted vmcnt(4) per
// iter (B keeps 4 loads in flight across iters; never drains in main loop). 2 phases/
// K-tile x 32 MFMA, raw s_barrier + asm waitcnt + sched_barrier + setprio. Math is
// bit-identical to R18 gemm1 (same K/h order) -> absmax must stay 0.03125.
// Predicted gemm1 ~62 -> ~45-50us, total ~292-300. Kill: gemm1 in top-5 / total>315.

typedef __bf16 bf16x8 __attribute__((ext_vector_type(8)));
typedef float f32x4 __attribute__((ext_vector_type(4)));
typedef ushort us8v __attribute__((ext_vector_type(8)));

#define BN_EPS 1e-3f

__device__ __forceinline__ ushort f2bf(float f) {
  union { float f; unsigned u; } v; v.f = f;
  unsigned r = (v.u + 0x7FFFu + ((v.u >> 16) & 1u)) >> 16;
  return (ushort)r;
}
__device__ __forceinline__ float bf2f(ushort b) {
  union { unsigned u; float f; } v; v.u = ((unsigned)b) << 16;
  return v.f;
}
__device__ __forceinline__ void async16(const void* g, void* l) {
  __builtin_amdgcn_global_load_lds((const __attribute__((address_space(1))) void*)g,
                                   (__attribute__((address_space(3))) void*)l, 16, 0, 0);
}

// ------- 1. prep: interleaved roles. 3969 blocks total:
//   b < 3845: b%5<4 -> transpose tIdx=(b/5)*4+b%5 ; b%5==4 -> other oIdx=b/5
//   b >= 3845: transpose tIdx = 3076 + (b-3845)
//   other: oIdx 0..511 = w1 conv | 512..767 = w2 conv (float4) | 768 = RoI frame-sort
__global__ __launch_bounds__(256, 6) void prep_kernel(const float* __restrict__ img,
                                                      ushort* __restrict__ imgTb,
                                                      const float* __restrict__ w1,
                                                      ushort* __restrict__ w1b,
                                                      const float* __restrict__ w2,
                                                      ushort* __restrict__ w2b,
                                                      const int* __restrict__ kf,
                                                      int* __restrict__ perm) {
  __shared__ __align__(16) char smem[25480];
  const int b = blockIdx.x;
  const int tid = threadIdx.x;
  int tIdx = -1, oIdx = -1;
  if (b < 3845) {
    int q = b / 5, r = b - q * 5;
    if (r < 4) tIdx = q * 4 + r; else oIdx = q;
  } else {
    tIdx = 3076 + (b - 3845);
  }
  if (tIdx >= 0) {
    ushort* lds = (ushort*)smem;  // [pixel][channel], pitch 260, 32 rows = 16,640B
    const int f = tIdx / 50, p0 = (tIdx % 50) * 32;
    const float* src = img + (size_t)f * 409600 + p0;
    float4 v[2][4];
#pragma unroll
    for (int m = 0; m < 2; ++m) {
      int g = m * 256 + tid;
      int cg = g >> 3;  // channel group (4 ch), 0..63
      int pg = g & 7;   // pixel group (4 px), 0..7
#pragma unroll
      for (int j = 0; j < 4; ++j)
        v[m][j] = *(const float4*)(src + (size_t)(cg * 4 + j) * 1600 + pg * 4);
    }
#pragma unroll
    for (int m = 0; m < 2; ++m) {
      int g = m * 256 + tid;
      int cg = g >> 3;
      int pg = g & 7;
#pragma unroll
      for (int i = 0; i < 4; ++i) {
        ushort4 o;
        o.x = f2bf((&v[m][0].x)[i]);
        o.y = f2bf((&v[m][1].x)[i]);
        o.z = f2bf((&v[m][2].x)[i]);
        o.w = f2bf((&v[m][3].x)[i]);
        *(ushort4*)(&lds[(pg * 4 + i) * 260 + cg * 4]) = o;
      }
    }
    __syncthreads();
    ushort* dst = imgTb + ((size_t)f * 1600 + p0) * 256;
#pragma unroll
    for (int q = 0; q < 4; ++q) {
      int p = q * 8 + (tid >> 5);  // 0..31
      int cg8 = tid & 31;
      ushort4 a = *(const ushort4*)(&lds[p * 260 + cg8 * 8]);
      ushort4 c = *(const ushort4*)(&lds[p * 260 + cg8 * 8 + 4]);
      us8v o;
      o[0] = a.x; o[1] = a.y; o[2] = a.z; o[3] = a.w;
      o[4] = c.x; o[5] = c.y; o[6] = c.z; o[7] = c.w;
      *(us8v*)(dst + (size_t)p * 256 + cg8 * 8) = o;
    }
  } else if (oIdx < 512) {
    // w1 [512][256][49] f32 -> w1b [512][49*256] bf16 (k = p*256+c); bf16 staging
    ushort* t = (ushort*)smem;  // [p][c], pitch 260, 49 rows = 25,480B
    const int o = oIdx;
    const float* src = w1 + (size_t)o * 12544;
    for (int j = tid; j < 12544; j += 256) {
      int c = j / 49, p = j - c * 49;
      t[p * 260 + c] = f2bf(src[j]);
    }
    __syncthreads();
    ushort* dst = w1b + (size_t)o * 12544;
    for (int k0 = tid * 8; k0 < 12544; k0 += 2048) {
      int p = k0 >> 8, c = k0 & 255;
      ushort4 a = *(const ushort4*)(&t[p * 260 + c]);
      ushort4 d = *(const ushort4*)(&t[p * 260 + c + 4]);
      us8v o8;
      o8[0] = a.x; o8[1] = a.y; o8[2] = a.z; o8[3] = a.w;
      o8[4] = d.x; o8[5] = d.y; o8[6] = d.z; o8[7] = d.w;
      *(us8v*)(dst + k0) = o8;
    }
  } else if (oIdx < 768) {
    // w2 [512][512] f32 -> bf16, float4 per thread
    const int o2 = oIdx - 512;
    const size_t base = (size_t)o2 * 1024 + tid * 4;
    float4 vv = *(const float4*)(w2 + base);
    ushort4 o4;
    o4.x = f2bf(vv.x); o4.y = f2bf(vv.y); o4.z = f2bf(vv.z); o4.w = f2bf(vv.w);
    *(ushort4*)(w2b + base) = o4;
  } else {
    // counting sort of RoIs by frame -> perm[4096]
    int* cnt = (int*)smem;
    int* base = cnt + 64;
    if (tid < 64) cnt[tid] = 0;
    __syncthreads();
    for (int r = tid; r < 4096; r += 256) atomicAdd(&cnt[kf[r]], 1);
    __syncthreads();
    if (tid == 0) {
      int acc = 0;
      for (int f = 0; f < 64; ++f) { base[f] = acc; acc += cnt[f]; }
    }
    __syncthreads();
    for (int r = tid; r < 4096; r += 256) {
      int p = atomicAdd(&base[kf[r]], 1);
      perm[p] = r;
    }
  }
}

// ------- 2. RoIAlign (bf16 image) -> A [4096][12544] bf16, k = (py*7+px)*256 + c ---------
__global__ __launch_bounds__(256) void roi_kernel(const ushort* __restrict__ imgTb,
                                                  const int* __restrict__ kf,
                                                  const float* __restrict__ boxes,
                                                  const int* __restrict__ perm,
                                                  ushort* __restrict__ A) {
  __shared__ int sy0[49], sx0[49], sy1[49], sx1[49];
  __shared__ float sw00[49], sw01[49], sw10[49], sw11[49];
  __shared__ int sf, sr;
  const int tid = threadIdx.x;
  if (tid == 0) {
    int r = perm[((blockIdx.x & 7) << 9) | (blockIdx.x >> 3)];
    sr = r;
    sf = kf[r];
  }
  __syncthreads();
  const int r = sr;
  if (tid < 49) {
    int py = tid / 7, px = tid % 7;
    float x1 = boxes[r * 4 + 0] * 40.f, y1 = boxes[r * 4 + 1] * 40.f;
    float x2 = boxes[r * 4 + 2] * 40.f, y2 = boxes[r * 4 + 3] * 40.f;
    float bw = (x2 - x1) * (1.f / 7.f), bh = (y2 - y1) * (1.f / 7.f);
    float X = x1 + (px + 0.5f) * bw, Y = y1 + (py + 0.5f) * bh;
    bool valid = (X > -1.f) && (X < 40.f) && (Y > -1.f) && (Y < 40.f);
    float x = fminf(fmaxf(X, 0.f), 39.f), y = fminf(fmaxf(Y, 0.f), 39.f);
    float x0f = floorf(x), y0f = floorf(y);
    int x0 = (int)x0f, y0 = (int)y0f;
    int x1i = min(x0 + 1, 39), y1i = min(y0 + 1, 39);
    float lx = x - x0f, ly = y - y0f;
    float vm = valid ? 1.f : 0.f;
    sx0[tid] = x0; sy0[tid] = y0; sx1[tid] = x1i; sy1[tid] = y1i;
    sw00[tid] = (1.f - ly) * (1.f - lx) * vm;
    sw01[tid] = (1.f - ly) * lx * vm;
    sw10[tid] = ly * (1.f - lx) * vm;
    sw11[tid] = ly * lx * vm;
  }
  __syncthreads();
  const int c8 = (tid & 31) * 8;
  const int pq = tid >> 5;
  const ushort* base = imgTb + (size_t)sf * 409600 + c8;
  ushort* outp = A + (size_t)r * 12544 + c8;
  for (int p = pq; p < 49; p += 8) {
    const us8v a = *(const us8v*)(base + (size_t)(sy0[p] * 40 + sx0[p]) * 256);
    const us8v b = *(const us8v*)(base + (size_t)(sy0[p] * 40 + sx1[p]) * 256);
    const us8v c = *(const us8v*)(base + (size_t)(sy1[p] * 40 + sx0[p]) * 256);
    const us8v d = *(const us8v*)(base + (size_t)(sy1[p] * 40 + sx1[p]) * 256);
    float w00 = sw00[p], w01 = sw01[p], w10 = sw10[p], w11 = sw11[p];
    us8v o;
#pragma unroll
    for (int k = 0; k < 8; ++k)
      o[k] = f2bf(bf2f(a[k]) * w00 + bf2f(b[k]) * w01 + bf2f(c[k]) * w10 + bf2f(d[k]) * w11);
    *(us8v*)(outp + (size_t)p * 256) = o;
  }
}

// ------- 3. GEMM1: 256x256 tile, BK=64, split-K=7, deep pipeline (T3+T4) ----------------
// A dbuf (2x32KB) + B triple buf (3x32KB) = 160KB LDS, 1 blk/CU, 8 waves (2Mx4N).
// Stage A(kt+1) in phase0, B(kt+2) in phase1; iter-end s_waitcnt vmcnt(4) retires
// {B(kt+1), A(kt+1)}, leaves B(kt+2)'s 4 loads in flight (counted, never drain-0).
// Swizzle: chunk s of row R holds global chunk s^(R&7) (same validated scheme as before).
__global__ __launch_bounds__(512, 2) void gemm1_kernel(const ushort* __restrict__ A,
                                                       const ushort* __restrict__ B,
                                                       ushort* __restrict__ P) {
  constexpr int K = 12544;
  constexpr int KS = 1792;  // per-z K range: 28 tiles of 64
  constexpr int NT = 28;
  __shared__ __align__(16) ushort sA[2][16384];  // 64 KB: 256r x 64k, double
  __shared__ __align__(16) ushort sB[3][16384];  // 96 KB: triple
  const int tid = threadIdx.x;
  const int lane = tid & 63, wave = tid >> 6;
  const int wm = wave >> 2, wn = wave & 3;      // 2 x 4 waves -> per-wave 128x64 out
  const int r16 = lane & 15, quad = lane >> 4;
  const int sw = r16 & 7;
  const int r0 = blockIdx.x * 256, c0 = blockIdx.y * 256;
  const int kStart = blockIdx.z * KS;
  const ushort* Ab = A + (size_t)r0 * K + kStart;
  const ushort* Bb = B + (size_t)c0 * K + kStart;
  const int row8 = tid >> 3;                       // 0..63
  const int koff = ((tid & 7) ^ (row8 & 7)) * 8;   // swizzled source chunk
  f32x4 acc[8][4] = {};

  // prologue: A(0)->sA0, B(0)->sB0, B(1)->sB1; retire first 8, keep B(1) in flight
#pragma unroll
  for (int s = 0; s < 4; ++s)
    async16(Ab + (size_t)(s * 64 + row8) * K + koff, (char*)sA[0] + s * 8192 + tid * 16);
#pragma unroll
  for (int s = 0; s < 4; ++s)
    async16(Bb + (size_t)(s * 64 + row8) * K + koff, (char*)sB[0] + s * 8192 + tid * 16);
#pragma unroll
  for (int s = 0; s < 4; ++s)
    async16(Bb + (size_t)(s * 64 + row8) * K + 64 + koff, (char*)sB[1] + s * 8192 + tid * 16);
  asm volatile("s_waitcnt vmcnt(4)" ::: "memory");
  __builtin_amdgcn_sched_barrier(0);
  __builtin_amdgcn_s_barrier();

  int Bcur = 0;
  for (int kt = 0; kt < NT; ++kt) {
    const int Acur = kt & 1;
    const ushort* a_base = sA[Acur];
    const ushort* b_base = sB[Bcur];
    bf16x8 bfr[4][2], af[4][2];
    // ---------- phase 0: read B(all j) + A(i 0..3); stage A(kt+1); MFMA upper half
#pragma unroll
    for (int j = 0; j < 4; ++j)
#pragma unroll
      for (int h = 0; h < 2; ++h)
        bfr[j][h] = *(const bf16x8*)(b_base + (wn * 64 + j * 16 + r16) * 64 +
                                     ((h * 4 + quad) ^ sw) * 8);
#pragma unroll
    for (int i = 0; i < 4; ++i)
#pragma unroll
      for (int h = 0; h < 2; ++h)
        af[i][h] = *(const bf16x8*)(a_base + (wm * 128 + i * 16 + r16) * 64 +
                                    ((h * 4 + quad) ^ sw) * 8);
    if (kt + 1 < NT) {
      const int kk1 = (kt + 1) * 64;
#pragma unroll
      for (int s = 0; s < 4; ++s)
        async16(Ab + (size_t)(s * 64 + row8) * K + kk1 + koff,
                (char*)sA[Acur ^ 1] + s * 8192 + tid * 16);
    }
    __builtin_amdgcn_s_barrier();
    asm volatile("s_waitcnt lgkmcnt(0)" ::: "memory");
    __builtin_amdgcn_sched_barrier(0);
    __builtin_amdgcn_s_setprio(1);
#pragma unroll
    for (int i = 0; i < 4; ++i)
#pragma unroll
      for (int j = 0; j < 4; ++j)
#pragma unroll
        for (int h = 0; h < 2; ++h)
          acc[i][j] =
              __builtin_amdgcn_mfma_f32_16x16x32_bf16(af[i][h], bfr[j][h], acc[i][j], 0, 0, 0);
    __builtin_amdgcn_s_setprio(0);
    __builtin_amdgcn_s_barrier();
    // ---------- phase 1: read A(i 4..7); stage B(kt+2); MFMA lower half
#pragma unroll
    for (int i = 0; i < 4; ++i)
#pragma unroll
      for (int h = 0; h < 2; ++h)
        af[i][h] = *(const bf16x8*)(a_base + (wm * 128 + (i + 4) * 16 + r16) * 64 +
                                    ((h * 4 + quad) ^ sw) * 8);
    if (kt + 2 < NT) {
      int b2 = Bcur + 2; if (b2 >= 3) b2 -= 3;
      const int kk2 = (kt + 2) * 64;
#pragma unroll
      for (int s = 0; s < 4; ++s)
        async16(Bb + (size_t)(s * 64 + row8) * K + kk2 + koff,
                (char*)sB[b2] + s * 8192 + tid * 16);
    }
    __builtin_amdgcn_s_barrier();
    asm volatile("s_waitcnt lgkmcnt(0)" ::: "memory");
    __builtin_amdgcn_sched_barrier(0);
    __builtin_amdgcn_s_setprio(1);
#pragma unroll
    for (int i = 0; i < 4; ++i)
#pragma unroll
      for (int j = 0; j < 4; ++j)
#pragma unroll
        for (int h = 0; h < 2; ++h)
          acc[i + 4][j] = __builtin_amdgcn_mfma_f32_16x16x32_bf16(af[i][h], bfr[j][h],
                                                                  acc[i + 4][j], 0, 0, 0);
    __builtin_amdgcn_s_setprio(0);
    // iter end: counted retire -> {B(kt+1), A(kt+1)} landed; B(kt+2) stays in flight
    if (kt + 2 < NT) {
      asm volatile("s_waitcnt vmcnt(4)" ::: "memory");
    } else {
      asm volatile("s_waitcnt vmcnt(0)" ::: "memory");
    }
    __builtin_amdgcn_sched_barrier(0);
    __builtin_amdgcn_s_barrier();
    Bcur = (Bcur + 1 == 3) ? 0 : Bcur + 1;
  }

  ushort* Pz = P + ((size_t)blockIdx.z * 4096 + r0) * 512 + c0;
#pragma unroll
  for (int i = 0; i < 8; ++i)
#pragma unroll
    for (int j = 0; j < 4; ++j)
#pragma unroll
      for (int g = 0; g < 4; ++g)
        Pz[(size_t)(wm * 128 + i * 16 + quad * 4 + g) * 512 + (wn * 64 + j * 16 + r16)] =
            f2bf(acc[i][j][g]);
}

// ------- 4. combine 7 split-K bf16 partials + b1 + BN1 + ReLU -> h1 bf16 -----------------
__global__ __launch_bounds__(256) void combine_kernel(const ushort* __restrict__ P,
                                                      const float* __restrict__ b1,
                                                      const float* __restrict__ g1,
                                                      const float* __restrict__ bt1,
                                                      const float* __restrict__ m1,
                                                      const float* __restrict__ v1,
                                                      ushort* __restrict__ h1) {
  const size_t i0 = ((size_t)blockIdx.x * 256 + threadIdx.x) * 8;  // 1024*256*8 = 4096*512
  const int col = (int)(i0 & 511);  // 8-aligned, no row crossing
  float x[8] = {};
#pragma unroll
  for (int z = 0; z < 7; ++z) {
    us8v pv = *(const us8v*)(P + i0 + (size_t)z * 2097152);
#pragma unroll
    for (int e = 0; e < 8; ++e) x[e] += bf2f(pv[e]);
  }
  us8v o;
#pragma unroll
  for (int e = 0; e < 8; ++e) {
    int c = col + e;
    float s = g1[c] * rsqrtf(v1[c] + BN_EPS);
    o[e] = f2bf(fmaxf((x[e] + b1[c] - m1[c]) * s + bt1[c], 0.f));
  }
  *(us8v*)(h1 + i0) = o;
}

// ------- 5. GEMM2 (64x128 tile, BK=64) + b2 + BN2 + ReLU + group-of-8 max -> out ---------
__global__ __launch_bounds__(256) void gemm2_kernel(const ushort* __restrict__ A,
                                                    const ushort* __restrict__ B,
                                                    const float* __restrict__ b2,
                                                    const float* __restrict__ g2,
                                                    const float* __restrict__ bt2,
                                                    const float* __restrict__ m2,
                                                    const float* __restrict__ v2,
                                                    float* __restrict__ out) {
  constexpr int K = 512;
  __shared__ __align__(16) ushort sA[64 * 64];   // 8 KB
  __shared__ __align__(16) ushort sB[128 * 64];  // 16 KB
  __shared__ ushort st[64 * 128];                // post-activation tile for group-max
  const int tid = threadIdx.x;
  const int lane = tid & 63, wave = tid >> 6;
  const int wm = wave >> 1, wn = wave & 1;
  const int r16 = lane & 15, quad = lane >> 4;
  const int r0 = blockIdx.x * 64, c0 = blockIdx.y * 128;
  const ushort* Ab = A + (size_t)r0 * K;
  const ushort* Bb = B + (size_t)c0 * K;
  const int row8 = tid >> 3;
  const int koff = (((tid & 7) ^ (row8 & 7))) * 8;
  const int sw = r16 & 7;
  f32x4 acc[2][4] = {};
  for (int kk = 0; kk < K; kk += 64) {
    __syncthreads();
#pragma unroll
    for (int s = 0; s < 2; ++s)
      async16(Ab + (size_t)(s * 32 + row8) * K + kk + koff, (char*)sA + s * 4096 + tid * 16);
#pragma unroll
    for (int s = 0; s < 4; ++s)
      async16(Bb + (size_t)(s * 32 + row8) * K + kk + koff, (char*)sB + s * 4096 + tid * 16);
    __syncthreads();
#pragma unroll
    for (int h = 0; h < 2; ++h) {
      const int slot = ((h * 4 + quad) ^ sw) * 8;
      bf16x8 af[2], bfr[4];
#pragma unroll
      for (int i = 0; i < 2; ++i)
        af[i] = *(const bf16x8*)(sA + (wm * 32 + i * 16 + r16) * 64 + slot);
#pragma unroll
      for (int j = 0; j < 4; ++j)
        bfr[j] = *(const bf16x8*)(sB + (wn * 64 + j * 16 + r16) * 64 + slot);
#pragma unroll
      for (int i = 0; i < 2; ++i)
#pragma unroll
        for (int j = 0; j < 4; ++j)
          acc[i][j] = __builtin_amdgcn_mfma_f32_16x16x32_bf16(af[i], bfr[j], acc[i][j], 0, 0, 0);
    }
  }
  float ss[4], tt[4], bbv[4];
#pragma unroll
  for (int j = 0; j < 4; ++j) {
    int c = c0 + wn * 64 + j * 16 + r16;
    float s = g2[c] * rsqrtf(v2[c] + BN_EPS);
    ss[j] = s; tt[j] = bt2[c] - m2[c] * s; bbv[j] = b2[c];
  }
#pragma unroll
  for (int i = 0; i < 2; ++i)
#pragma unroll
    for (int j = 0; j < 4; ++j)
#pragma unroll
      for (int g = 0; g < 4; ++g) {
        int rr = wm * 32 + i * 16 + quad * 4 + g;
        int cc = wn * 64 + j * 16 + r16;
        float x = (acc[i][j][g] + bbv[j]) * ss[j] + tt[j];
        st[rr * 128 + cc] = f2bf(fmaxf(x, 0.f));
      }
  __syncthreads();
  for (int e = tid; e < 1024; e += 256) {
    int gg = e >> 7, cc = e & 127;
    float m = 0.f;  // relu output >= 0
#pragma unroll
    for (int k = 0; k < 8; ++k) m = fmaxf(m, bf2f(st[(gg * 8 + k) * 128 + cc]));
    out[(size_t)(r0 / 8 + gg) * 512 + c0 + cc] = m;
  }
}

extern "C" void kernel_launch(void* const* d_in, const int* in_sizes, int n_in,
                              void* d_out, int out_size, void* d_ws, size_t ws_size,
                              hipStream_t stream) {
  (void)in_sizes; (void)n_in; (void)out_size; (void)ws_size;
  const float* images = (const float*)d_in[0];
  const int* kf      = (const int*)d_in[1];
  const float* boxes = (const float*)d_in[2];
  const float* w1    = (const float*)d_in[3];
  const float* b1    = (const float*)d_in[4];
  const float* g1    = (const float*)d_in[5];
  const float* bt1   = (const float*)d_in[6];
  const float* m1    = (const float*)d_in[7];
  const float* v1    = (const float*)d_in[8];
  const float* w2    = (const float*)d_in[9];
  const float* b2    = (const float*)d_in[10];
  const float* g2    = (const float*)d_in[11];
  const float* bt2   = (const float*)d_in[12];
  const float* m2    = (const float*)d_in[13];
  const float* v2    = (const float*)d_in[14];
  float* out = (float*)d_out;

  char* ws = (char*)d_ws;
  // layout (bytes):  [ws_size >= 221 MB proven earlier]
  //   A     @ 0          : 4096*12544*2 = 102,760,448
  //   w1b   @ 102,760,448: 512*12544*2  =  12,845,056
  //   w2b   @ 115,605,504: 512*512*2    =     524,288
  //   imgTb @ 116,129,792: 64*1600*256*2 = 52,428,800 -> ends 168,558,592 (dead after roi)
  //   P     @ 116,129,792: 7*4096*512*2 = 29,360,128  (aliases imgTb head; written post-roi)
  //   h1    @ 149,684,224: 4096*512*2   =  4,194,304  (aliases imgTb mid; written post-roi)
  //   perm  @ 168,558,592: 4096*4       =      16,384 (strictly after imgTb end!)
  ushort* Abuf  = (ushort*)(ws + 0);
  ushort* w1b   = (ushort*)(ws + 102760448);
  ushort* w2b   = (ushort*)(ws + 115605504);
  ushort* imgTb = (ushort*)(ws + 116129792);
  ushort* P     = (ushort*)(ws + 116129792);
  ushort* h1    = (ushort*)(ws + 149684224);
  int*    perm  = (int*)(ws + 168558592);

  hipLaunchKernelGGL(prep_kernel, dim3(3969), dim3(256), 0, stream,
                     images, imgTb, w1, w1b, w2, w2b, kf, perm);
  hipLaunchKernelGGL(roi_kernel, dim3(4096), dim3(256), 0, stream, imgTb, kf, boxes, perm, Abuf);
  hipLaunchKernelGGL(gemm1_kernel, dim3(16, 2, 7), dim3(512), 0, stream, Abuf, w1b, P);
  hipLaunchKernelGGL(combine_kernel, dim3(1024), dim3(256), 0, stream, P, b1, g1, bt1, m1, v1, h1);
  hipLaunchKernelGGL(gemm2_kernel, dim3(64, 4), dim3(256), 0, stream, h1, w2b, b2, g2, bt2, m2, v2, out);
}